// Round 5
// baseline (1333.399 us; speedup 1.0000x reference)
//
#include <hip/hip_runtime.h>
#include <hip/hip_bf16.h>

#define N_NODES 100000
#define N_EDGES 1600000
#define HID 64
#define OUT_CH 32

// bucketed CSR parameters. dst is uniform-random over 100000 nodes, so per-
// bucket edge count ~ Binomial(1.6M, 512/1e5): mean 8192, sigma ~90.
// BKCAP = mean + 22 sigma. Node degree ~ Binomial(1.6M, 1e-5): mean 16 —
// fits the 11-bit deg field of the packed off|deg word with huge margin.
#define NB 196          // ceil(100000/512) buckets of 512 consecutive dst nodes
#define BKCAP 10240     // per-bucket record capacity (padded layout)
#define EPB 2048        // edges per partition block
#define NP ((N_EDGES + EPB - 1) / EPB)  // 782 partition blocks
#define SLOTS 32        // LDS slots per bucket per block (mean 10.5, +6.7 sigma)

// ---- edge_index dtype probe: int64 => all odd 32-bit words are 0 -----------
__global__ void detect_kernel(const int* __restrict__ ei, int* __restrict__ flag) {
    int i = threadIdx.x;  // 0..63
    int v = ei[2 * i + 1];
    unsigned long long ball = __ballot(v == 0);
    if (i == 0) *flag = (ball == ~0ull) ? 1 : 0;  // 1 = int64, 0 = int32
}

__device__ __forceinline__ int get_idx(const int* __restrict__ ei, int is64, long long pos) {
    return is64 ? ei[2 * pos] : ei[pos];
}

// ---- gcur[b] = b*BKCAP ----------------------------------------------------
__global__ void bucket_init_kernel(int* __restrict__ gcur) {
    int t = threadIdx.x;
    if (t < NB) gcur[t] = t * BKCAP;
}

// ---- phase 1: partition edges into fixed-cap dst buckets ------------------
// record = (dst&511)<<17 | src   (src < 2^17)
__global__ void __launch_bounds__(256) partition_kernel(
        const int* __restrict__ ei, const int* __restrict__ flag,
        int* __restrict__ gcur, int* __restrict__ bkt) {
    __shared__ int lcount[NB];
    __shared__ int lbuf[NB * SLOTS];
    int tid = threadIdx.x;
    for (int i = tid; i < NB; i += 256) lcount[i] = 0;
    __syncthreads();
    int is64 = *flag;
    int e0 = blockIdx.x * EPB;
    int e1 = min(e0 + EPB, N_EDGES);
    for (int e = e0 + tid; e < e1; e += 256) {
        int s = get_idx(ei, is64, e);
        int d = get_idx(ei, is64, (long long)N_EDGES + e);
        int val = ((d & 511) << 17) | s;
        int bk = d >> 9;
        int c = atomicAdd(&lcount[bk], 1);
        if (c < SLOTS) {
            lbuf[bk * SLOTS + c] = val;
        } else {  // rare overflow (~1e-3 events/grid): direct global append
            int p = atomicAdd(&gcur[bk], 1);
            bkt[p] = val;
        }
    }
    __syncthreads();
    int wid = tid >> 6, lane = tid & 63;
    for (int bk = wid; bk < NB; bk += 4) {
        int cnt = min(lcount[bk], SLOTS);
        int base;
        if (lane == 0) base = atomicAdd(&gcur[bk], cnt);
        base = __shfl(base, 0);
        for (int i = lane; i < cnt; i += 64) bkt[base + i] = lbuf[bk * SLOTS + i];
    }
}

// ---- phase 2: per-bucket csr build in LDS + packed off|deg ----------------
// offpk[n] = (abs_off & 0x1FFFFF) | (deg << 21)
__global__ void __launch_bounds__(256) bucket_fill_kernel(
        const int* __restrict__ gcur, const int* __restrict__ bkt,
        int* __restrict__ csr, unsigned int* __restrict__ offpk) {
    __shared__ int lcnt[512];
    __shared__ int loff[512];
    __shared__ int lcur[512];
    __shared__ int ps[256];
    __shared__ int scsr[BKCAP];
    int b = blockIdx.x;
    int tid = threadIdx.x;
    int base = b * BKCAP;
    int m = gcur[b] - base;               // records in this bucket
    int n0 = b << 9;
    int nn = min(512, N_NODES - n0);

    lcnt[tid] = 0;
    lcnt[tid + 256] = 0;
    __syncthreads();
    // pass 1: per-node counts
    for (int i = tid; i < m; i += 256) atomicAdd(&lcnt[bkt[base + i] >> 17], 1);
    __syncthreads();
    // 512-wide exclusive scan: pair-sums then Hillis-Steele over 256
    int a0 = lcnt[2 * tid], a1 = lcnt[2 * tid + 1];
    int pv = a0 + a1;
    ps[tid] = pv;
    __syncthreads();
    for (int d = 1; d < 256; d <<= 1) {
        int t = (tid >= d) ? ps[tid - d] : 0;
        __syncthreads();
        ps[tid] += t;
        __syncthreads();
    }
    int excl = ps[tid] - pv;
    loff[2 * tid] = excl;
    loff[2 * tid + 1] = excl + a0;
    lcur[2 * tid] = excl;
    lcur[2 * tid + 1] = excl + a0;
    __syncthreads();
    // pass 2: place records
    bool fit = (m <= BKCAP);  // always true by construction
    for (int i = tid; i < m; i += 256) {
        int val = bkt[base + i];
        int dl = val >> 17;
        int p = atomicAdd(&lcur[dl], 1);
        if (fit) scsr[p] = val & 0x1FFFF;
        else csr[base + p] = val & 0x1FFFF;
    }
    __syncthreads();
    if (fit)
        for (int i = tid; i < m; i += 256) csr[base + i] = scsr[i];
    // packed per-node offset|degree
    for (int i = tid; i < nn; i += 256)
        offpk[n0 + i] = (unsigned int)((base + loff[i]) | (lcnt[i] << 21));
}

// ---- gather-aggregate: one wave per node, lane = channel; inv_deg folded --
__global__ void __launch_bounds__(256) gather_kernel(
        const float* __restrict__ h, const unsigned int* __restrict__ offpk,
        const int* __restrict__ csr, float* __restrict__ agg) {
    int node = blockIdx.x * 4 + (threadIdx.x >> 6);
    if (node >= N_NODES) return;
    int o = threadIdx.x & 63;
    unsigned int v = offpk[node];
    int off0 = (int)(v & 0x1FFFFFu);
    int cnt = (int)(v >> 21);
    int off1 = off0 + cnt;
    float acc = 0.f;
    int e = off0;
    int end4 = off0 + (cnt & ~3);
    for (; e < end4; e += 4) {
        int s0 = csr[e], s1 = csr[e + 1], s2 = csr[e + 2], s3 = csr[e + 3];
        float v0 = h[(size_t)s0 * HID + o];
        float v1 = h[(size_t)s1 * HID + o];
        float v2 = h[(size_t)s2 * HID + o];
        float v3 = h[(size_t)s3 * HID + o];
        acc += v0 + v1 + v2 + v3;
    }
    for (; e < off1; ++e) acc += h[(size_t)csr[e] * HID + o];
    float inv = 1.f / fmaxf((float)cnt, 1.f);
    agg[(size_t)node * HID + o] = acc * inv;
}

// ---- layer GEMM: out = relu(agg@Wl + h@Wr + b), 64-node LDS tile ----------
#define LT 68
__global__ void __launch_bounds__(256) layer_kernel(
        const float* __restrict__ agg, const float* __restrict__ h,
        const float* __restrict__ Wl, const float* __restrict__ Wr,
        const float* __restrict__ bias, float* __restrict__ out) {
    __shared__ float sWl[HID * HID];
    __shared__ float sWr[HID * HID];
    __shared__ float sAT[HID * LT];
    __shared__ float sHT[HID * LT];
    __shared__ float sb[HID];
    int tid = threadIdx.x;
    for (int i = tid; i < HID * HID; i += 256) {
        sWl[i] = Wl[i];
        sWr[i] = Wr[i];
    }
    if (tid < HID) sb[tid] = bias[tid];

    int node0 = blockIdx.x * 64;
    int rr = tid >> 4;           // 0..15
    int cc = (tid & 15) << 2;    // 0,4,...,60
#pragma unroll
    for (int p = 0; p < 4; ++p) {
        int r = rr + p * 16;
        int n = node0 + r;
        float4 a, hh;
        if (n < N_NODES) {
            a = *(const float4*)(agg + (size_t)n * HID + cc);
            hh = *(const float4*)(h + (size_t)n * HID + cc);
        } else {
            a = make_float4(0, 0, 0, 0);
            hh = make_float4(0, 0, 0, 0);
        }
        sAT[(cc + 0) * LT + r] = a.x;  sAT[(cc + 1) * LT + r] = a.y;
        sAT[(cc + 2) * LT + r] = a.z;  sAT[(cc + 3) * LT + r] = a.w;
        sHT[(cc + 0) * LT + r] = hh.x; sHT[(cc + 1) * LT + r] = hh.y;
        sHT[(cc + 2) * LT + r] = hh.z; sHT[(cc + 3) * LT + r] = hh.w;
    }
    __syncthreads();

    int c0 = (tid & 15) << 2;
    int n0 = (tid >> 4) << 2;
    float acc[4][4];
#pragma unroll
    for (int i = 0; i < 4; ++i)
#pragma unroll
        for (int j = 0; j < 4; ++j) acc[i][j] = sb[c0 + j];

#pragma unroll 8
    for (int k = 0; k < HID; ++k) {
        float4 wl = *(const float4*)&sWl[k * HID + c0];
        float4 wr = *(const float4*)&sWr[k * HID + c0];
        float4 a4 = *(const float4*)&sAT[k * LT + n0];
        float4 h4 = *(const float4*)&sHT[k * LT + n0];
        const float* ap = (const float*)&a4;
        const float* hp = (const float*)&h4;
        const float* wlp = (const float*)&wl;
        const float* wrp = (const float*)&wr;
#pragma unroll
        for (int i = 0; i < 4; ++i)
#pragma unroll
            for (int j = 0; j < 4; ++j)
                acc[i][j] += ap[i] * wlp[j] + hp[i] * wrp[j];
    }

#pragma unroll
    for (int i = 0; i < 4; ++i) {
        int n = node0 + n0 + i;
        if (n < N_NODES) {
            float4 o4;
            o4.x = fmaxf(acc[i][0], 0.f);
            o4.y = fmaxf(acc[i][1], 0.f);
            o4.z = fmaxf(acc[i][2], 0.f);
            o4.w = fmaxf(acc[i][3], 0.f);
            *(float4*)(out + (size_t)n * HID + c0) = o4;
        }
    }
}

// ---- final head: out = h @ Wlin + blin (fp32 out) -------------------------
__global__ void __launch_bounds__(256) final_kernel(
        const float* __restrict__ h, const float* __restrict__ W,
        const float* __restrict__ b, float* __restrict__ out) {
    __shared__ float sW[HID * OUT_CH];
    __shared__ float sb[OUT_CH];
    int tid = threadIdx.x;
    for (int i = tid; i < HID * OUT_CH; i += 256) sW[i] = W[i];
    if (tid < OUT_CH) sb[tid] = b[tid];
    __syncthreads();

    int node = blockIdx.x * 8 + (tid >> 5);
    if (node >= N_NODES) return;
    int o = tid & 31;
    const float* hr = h + (size_t)node * HID;
    float acc = sb[o];
#pragma unroll 8
    for (int k = 0; k < HID; k++) acc += hr[k] * sW[k * OUT_CH + o];
    out[(size_t)node * OUT_CH + o] = acc;
}

extern "C" void kernel_launch(void* const* d_in, const int* in_sizes, int n_in,
                              void* d_out, int out_size, void* d_ws, size_t ws_size,
                              hipStream_t stream) {
    const float* x    = (const float*)d_in[0];
    const int*   ei   = (const int*)d_in[1];
    const float* Wl1  = (const float*)d_in[2];
    const float* Wr1  = (const float*)d_in[3];
    const float* b1   = (const float*)d_in[4];
    const float* Wl2  = (const float*)d_in[5];
    const float* Wr2  = (const float*)d_in[6];
    const float* b2   = (const float*)d_in[7];
    const float* Wl3  = (const float*)d_in[8];
    const float* Wr3  = (const float*)d_in[9];
    const float* b3   = (const float*)d_in[10];
    const float* Wlin = (const float*)d_in[11];
    const float* blin = (const float*)d_in[12];
    float* out = (float*)d_out;

    // workspace layout (4-byte elements), ~59.6 MB total
    int* ip              = (int*)d_ws;
    int* flag            = ip;                         // 128
    unsigned int* offpk  = (unsigned int*)(flag + 128);// 100096
    int* gcur            = (int*)(offpk + 100096);     // 256
    int* csr             = gcur + 256;                 // NB*BKCAP = 2,007,040
    float* agg           = (float*)(csr + NB * BKCAP); // 6.4M floats
    float* feat          = agg + (size_t)N_NODES * HID;// 6.4M floats
    int* bkt             = (int*)agg;  // bucket records alias agg (dead until gather)

    const int GATHER_BLOCKS = (N_NODES + 3) / 4; // 25000
    const int LAYER_BLOCKS = (N_NODES + 63) / 64;// 1563
    const int FINAL_BLOCKS = (N_NODES + 7) / 8;  // 12500

    // CSR build: detect -> init cursors -> partition -> per-bucket fill
    detect_kernel<<<1, 64, 0, stream>>>(ei, flag);
    bucket_init_kernel<<<1, 256, 0, stream>>>(gcur);
    partition_kernel<<<NP, 256, 0, stream>>>(ei, flag, gcur, bkt);
    bucket_fill_kernel<<<NB, 256, 0, stream>>>(gcur, bkt, csr, offpk);

    // layer 1: x -> feat
    gather_kernel<<<GATHER_BLOCKS, 256, 0, stream>>>(x, offpk, csr, agg);
    layer_kernel<<<LAYER_BLOCKS, 256, 0, stream>>>(agg, x, Wl1, Wr1, b1, feat);

    // layer 2: feat -> feat (in-place safe: tile staged in LDS before write)
    gather_kernel<<<GATHER_BLOCKS, 256, 0, stream>>>(feat, offpk, csr, agg);
    layer_kernel<<<LAYER_BLOCKS, 256, 0, stream>>>(agg, feat, Wl2, Wr2, b2, feat);

    // layer 3
    gather_kernel<<<GATHER_BLOCKS, 256, 0, stream>>>(feat, offpk, csr, agg);
    layer_kernel<<<LAYER_BLOCKS, 256, 0, stream>>>(agg, feat, Wl3, Wr3, b3, feat);

    // head
    final_kernel<<<FINAL_BLOCKS, 256, 0, stream>>>(feat, Wlin, blin, out);
}

// Round 6
// 473.322 us; speedup vs baseline: 2.8171x; 2.8171x over previous
//
#include <hip/hip_runtime.h>
#include <hip/hip_bf16.h>

#define N_NODES 100000
#define N_EDGES 1600000
#define HID 64
#define OUT_CH 32

// Deterministic radix partition into dst buckets. Zero global atomics:
// per-block histograms + scans give exact write offsets (R5 post-mortem:
// contended global atomic cursors serialize at ~6 ns/atomic device-wide).
#define NB 196          // ceil(100000/512) buckets of 512 consecutive dst nodes
#define P 512           // partition blocks
#define EPP ((N_EDGES + P - 1) / P)   // 3125 edges per block
#define BKCAP 10240     // LDS csr staging cap (bucket mean 8192, sigma ~90)

// ---- edge_index dtype probe: int64 => all odd 32-bit words are 0 -----------
__global__ void detect_kernel(const int* __restrict__ ei, int* __restrict__ flag) {
    int i = threadIdx.x;  // 0..63
    int v = ei[2 * i + 1];
    unsigned long long ball = __ballot(v == 0);
    if (i == 0) *flag = (ball == ~0ull) ? 1 : 0;  // 1 = int64, 0 = int32
}

__device__ __forceinline__ int get_idx(const int* __restrict__ ei, int is64, long long pos) {
    return is64 ? ei[2 * pos] : ei[pos];
}

// ---- pass 1: per-block bucket histograms ----------------------------------
__global__ void __launch_bounds__(256) hist_kernel(
        const int* __restrict__ ei, const int* __restrict__ flag,
        int* __restrict__ histG) {
    __shared__ int lh[NB];
    int tid = threadIdx.x;
    for (int i = tid; i < NB; i += 256) lh[i] = 0;
    __syncthreads();
    int is64 = *flag;
    int e0 = blockIdx.x * EPP;
    int e1 = min(e0 + EPP, N_EDGES);
    for (int e = e0 + tid; e < e1; e += 256) {
        int d = get_idx(ei, is64, (long long)N_EDGES + e);
        atomicAdd(&lh[d >> 9], 1);
    }
    __syncthreads();
    for (int i = tid; i < NB; i += 256) histG[i * P + blockIdx.x] = lh[i];
}

// ---- per-bucket exclusive scan over P block-counts; emit bucket totals ----
__global__ void __launch_bounds__(256) scan_kernel(int* __restrict__ histG,
                                                   int* __restrict__ btot) {
    __shared__ int ps[256];
    int b = blockIdx.x;
    int tid = threadIdx.x;
    int v0 = histG[b * P + 2 * tid];
    int v1 = histG[b * P + 2 * tid + 1];
    int pv = v0 + v1;
    ps[tid] = pv;
    __syncthreads();
    for (int d = 1; d < 256; d <<= 1) {
        int t = (tid >= d) ? ps[tid - d] : 0;
        __syncthreads();
        ps[tid] += t;
        __syncthreads();
    }
    int excl = ps[tid] - pv;
    histG[b * P + 2 * tid] = excl;
    histG[b * P + 2 * tid + 1] = excl + v0;
    if (tid == 255) btot[b] = ps[255];
}

// ---- exclusive scan of 196 bucket totals -> dense bucket bases ------------
__global__ void base_scan_kernel(const int* __restrict__ btot, int* __restrict__ bbase) {
    __shared__ int s[256];
    int tid = threadIdx.x;
    int v = (tid < NB) ? btot[tid] : 0;
    s[tid] = v;
    __syncthreads();
    for (int d = 1; d < 256; d <<= 1) {
        int t = (tid >= d) ? s[tid - d] : 0;
        __syncthreads();
        s[tid] += t;
        __syncthreads();
    }
    if (tid < NB) bbase[tid] = s[tid] - v;
}

// ---- pass 2: place records at deterministic offsets (LDS cursors only) ----
// record = (dst&511)<<17 | src   (src < 2^17)
__global__ void __launch_bounds__(256) place_kernel(
        const int* __restrict__ ei, const int* __restrict__ flag,
        const int* __restrict__ histG, const int* __restrict__ bbase,
        int* __restrict__ bkt) {
    __shared__ int lcur[NB];
    int tid = threadIdx.x;
    for (int i = tid; i < NB; i += 256)
        lcur[i] = bbase[i] + histG[i * P + blockIdx.x];
    __syncthreads();
    int is64 = *flag;
    int e0 = blockIdx.x * EPP;
    int e1 = min(e0 + EPP, N_EDGES);
    for (int e = e0 + tid; e < e1; e += 256) {
        int s = get_idx(ei, is64, e);
        int d = get_idx(ei, is64, (long long)N_EDGES + e);
        int val = ((d & 511) << 17) | s;
        int p = atomicAdd(&lcur[d >> 9], 1);
        bkt[p] = val;
    }
}

// ---- per-bucket csr build in LDS + packed off|deg -------------------------
// offpk[n] = (abs_off & 0x1FFFFF) | (deg << 21);  off < 1.6M < 2^21, deg < 64
__global__ void __launch_bounds__(256) bucket_fill_kernel(
        const int* __restrict__ bbase, const int* __restrict__ btot,
        const int* __restrict__ bkt, int* __restrict__ csr,
        unsigned int* __restrict__ offpk) {
    __shared__ int lcnt[512];
    __shared__ int loff[512];
    __shared__ int lcur[512];
    __shared__ int ps[256];
    __shared__ int scsr[BKCAP];
    int b = blockIdx.x;
    int tid = threadIdx.x;
    int base = bbase[b];
    int m = btot[b];
    int n0 = b << 9;
    int nn = min(512, N_NODES - n0);

    lcnt[tid] = 0;
    lcnt[tid + 256] = 0;
    __syncthreads();
    for (int i = tid; i < m; i += 256) atomicAdd(&lcnt[bkt[base + i] >> 17], 1);
    __syncthreads();
    int a0 = lcnt[2 * tid], a1 = lcnt[2 * tid + 1];
    int pv = a0 + a1;
    ps[tid] = pv;
    __syncthreads();
    for (int d = 1; d < 256; d <<= 1) {
        int t = (tid >= d) ? ps[tid - d] : 0;
        __syncthreads();
        ps[tid] += t;
        __syncthreads();
    }
    int excl = ps[tid] - pv;
    loff[2 * tid] = excl;
    loff[2 * tid + 1] = excl + a0;
    lcur[2 * tid] = excl;
    lcur[2 * tid + 1] = excl + a0;
    __syncthreads();
    bool fit = (m <= BKCAP);  // always true (mean 8192 + 22 sigma < BKCAP)
    for (int i = tid; i < m; i += 256) {
        int val = bkt[base + i];
        int dl = val >> 17;
        int p = atomicAdd(&lcur[dl], 1);
        if (fit) scsr[p] = val & 0x1FFFF;
        else csr[base + p] = val & 0x1FFFF;
    }
    __syncthreads();
    if (fit)
        for (int i = tid; i < m; i += 256) csr[base + i] = scsr[i];
    for (int i = tid; i < nn; i += 256)
        offpk[n0 + i] = (unsigned int)((base + loff[i]) | (lcnt[i] << 21));
}

// ---- gather-aggregate: one wave per node, lane = channel; inv_deg folded --
__global__ void __launch_bounds__(256) gather_kernel(
        const float* __restrict__ h, const unsigned int* __restrict__ offpk,
        const int* __restrict__ csr, float* __restrict__ agg) {
    int node = blockIdx.x * 4 + (threadIdx.x >> 6);
    if (node >= N_NODES) return;
    int o = threadIdx.x & 63;
    unsigned int v = offpk[node];
    int off0 = (int)(v & 0x1FFFFFu);
    int cnt = (int)(v >> 21);
    int off1 = off0 + cnt;
    float acc = 0.f;
    int e = off0;
    int end4 = off0 + (cnt & ~3);
    for (; e < end4; e += 4) {
        int s0 = csr[e], s1 = csr[e + 1], s2 = csr[e + 2], s3 = csr[e + 3];
        float v0 = h[(size_t)s0 * HID + o];
        float v1 = h[(size_t)s1 * HID + o];
        float v2 = h[(size_t)s2 * HID + o];
        float v3 = h[(size_t)s3 * HID + o];
        acc += v0 + v1 + v2 + v3;
    }
    for (; e < off1; ++e) acc += h[(size_t)csr[e] * HID + o];
    float inv = 1.f / fmaxf((float)cnt, 1.f);
    agg[(size_t)node * HID + o] = acc * inv;
}

// ---- layer GEMM: out = relu(agg@Wl + h@Wr + b), 64-node LDS tile ----------
#define LT 68
__global__ void __launch_bounds__(256) layer_kernel(
        const float* __restrict__ agg, const float* __restrict__ h,
        const float* __restrict__ Wl, const float* __restrict__ Wr,
        const float* __restrict__ bias, float* __restrict__ out) {
    __shared__ float sWl[HID * HID];
    __shared__ float sWr[HID * HID];
    __shared__ float sAT[HID * LT];
    __shared__ float sHT[HID * LT];
    __shared__ float sb[HID];
    int tid = threadIdx.x;
    for (int i = tid; i < HID * HID; i += 256) {
        sWl[i] = Wl[i];
        sWr[i] = Wr[i];
    }
    if (tid < HID) sb[tid] = bias[tid];

    int node0 = blockIdx.x * 64;
    int rr = tid >> 4;           // 0..15
    int cc = (tid & 15) << 2;    // 0,4,...,60
#pragma unroll
    for (int p = 0; p < 4; ++p) {
        int r = rr + p * 16;
        int n = node0 + r;
        float4 a, hh;
        if (n < N_NODES) {
            a = *(const float4*)(agg + (size_t)n * HID + cc);
            hh = *(const float4*)(h + (size_t)n * HID + cc);
        } else {
            a = make_float4(0, 0, 0, 0);
            hh = make_float4(0, 0, 0, 0);
        }
        sAT[(cc + 0) * LT + r] = a.x;  sAT[(cc + 1) * LT + r] = a.y;
        sAT[(cc + 2) * LT + r] = a.z;  sAT[(cc + 3) * LT + r] = a.w;
        sHT[(cc + 0) * LT + r] = hh.x; sHT[(cc + 1) * LT + r] = hh.y;
        sHT[(cc + 2) * LT + r] = hh.z; sHT[(cc + 3) * LT + r] = hh.w;
    }
    __syncthreads();

    int c0 = (tid & 15) << 2;
    int n0 = (tid >> 4) << 2;
    float acc[4][4];
#pragma unroll
    for (int i = 0; i < 4; ++i)
#pragma unroll
        for (int j = 0; j < 4; ++j) acc[i][j] = sb[c0 + j];

#pragma unroll 8
    for (int k = 0; k < HID; ++k) {
        float4 wl = *(const float4*)&sWl[k * HID + c0];
        float4 wr = *(const float4*)&sWr[k * HID + c0];
        float4 a4 = *(const float4*)&sAT[k * LT + n0];
        float4 h4 = *(const float4*)&sHT[k * LT + n0];
        const float* ap = (const float*)&a4;
        const float* hp = (const float*)&h4;
        const float* wlp = (const float*)&wl;
        const float* wrp = (const float*)&wr;
#pragma unroll
        for (int i = 0; i < 4; ++i)
#pragma unroll
            for (int j = 0; j < 4; ++j)
                acc[i][j] += ap[i] * wlp[j] + hp[i] * wrp[j];
    }

#pragma unroll
    for (int i = 0; i < 4; ++i) {
        int n = node0 + n0 + i;
        if (n < N_NODES) {
            float4 o4;
            o4.x = fmaxf(acc[i][0], 0.f);
            o4.y = fmaxf(acc[i][1], 0.f);
            o4.z = fmaxf(acc[i][2], 0.f);
            o4.w = fmaxf(acc[i][3], 0.f);
            *(float4*)(out + (size_t)n * HID + c0) = o4;
        }
    }
}

// ---- final head: out = h @ Wlin + blin (fp32 out) -------------------------
__global__ void __launch_bounds__(256) final_kernel(
        const float* __restrict__ h, const float* __restrict__ W,
        const float* __restrict__ b, float* __restrict__ out) {
    __shared__ float sW[HID * OUT_CH];
    __shared__ float sb[OUT_CH];
    int tid = threadIdx.x;
    for (int i = tid; i < HID * OUT_CH; i += 256) sW[i] = W[i];
    if (tid < OUT_CH) sb[tid] = b[tid];
    __syncthreads();

    int node = blockIdx.x * 8 + (tid >> 5);
    if (node >= N_NODES) return;
    int o = tid & 31;
    const float* hr = h + (size_t)node * HID;
    float acc = sb[o];
#pragma unroll 8
    for (int k = 0; k < HID; k++) acc += hr[k] * sW[k * OUT_CH + o];
    out[(size_t)node * OUT_CH + o] = acc;
}

extern "C" void kernel_launch(void* const* d_in, const int* in_sizes, int n_in,
                              void* d_out, int out_size, void* d_ws, size_t ws_size,
                              hipStream_t stream) {
    const float* x    = (const float*)d_in[0];
    const int*   ei   = (const int*)d_in[1];
    const float* Wl1  = (const float*)d_in[2];
    const float* Wr1  = (const float*)d_in[3];
    const float* b1   = (const float*)d_in[4];
    const float* Wl2  = (const float*)d_in[5];
    const float* Wr2  = (const float*)d_in[6];
    const float* b2   = (const float*)d_in[7];
    const float* Wl3  = (const float*)d_in[8];
    const float* Wr3  = (const float*)d_in[9];
    const float* b3   = (const float*)d_in[10];
    const float* Wlin = (const float*)d_in[11];
    const float* blin = (const float*)d_in[12];
    float* out = (float*)d_out;

    // workspace layout (4-byte elements), ~58.6 MB total
    int* ip              = (int*)d_ws;
    int* flag            = ip;                          // 128
    unsigned int* offpk  = (unsigned int*)(flag + 128); // 100096
    int* bbase           = (int*)(offpk + 100096);      // 256
    int* btot            = bbase + 256;                 // 256
    int* histG           = btot + 256;                  // NB*P = 100352
    int* csr             = histG + NB * P;              // 1600000 (dense)
    float* agg           = (float*)(csr + N_EDGES);     // 6.4M floats
    float* feat          = agg + (size_t)N_NODES * HID; // 6.4M floats
    int* bkt             = (int*)agg;  // bucket records alias agg (dead until gather)

    const int GATHER_BLOCKS = (N_NODES + 3) / 4; // 25000
    const int LAYER_BLOCKS = (N_NODES + 63) / 64;// 1563
    const int FINAL_BLOCKS = (N_NODES + 7) / 8;  // 12500

    // CSR build: deterministic radix partition + per-bucket LDS fill
    detect_kernel<<<1, 64, 0, stream>>>(ei, flag);
    hist_kernel<<<P, 256, 0, stream>>>(ei, flag, histG);
    scan_kernel<<<NB, 256, 0, stream>>>(histG, btot);
    base_scan_kernel<<<1, 256, 0, stream>>>(btot, bbase);
    place_kernel<<<P, 256, 0, stream>>>(ei, flag, histG, bbase, bkt);
    bucket_fill_kernel<<<NB, 256, 0, stream>>>(bbase, btot, bkt, csr, offpk);

    // layer 1: x -> feat
    gather_kernel<<<GATHER_BLOCKS, 256, 0, stream>>>(x, offpk, csr, agg);
    layer_kernel<<<LAYER_BLOCKS, 256, 0, stream>>>(agg, x, Wl1, Wr1, b1, feat);

    // layer 2: feat -> feat (in-place safe: tile staged in LDS before write)
    gather_kernel<<<GATHER_BLOCKS, 256, 0, stream>>>(feat, offpk, csr, agg);
    layer_kernel<<<LAYER_BLOCKS, 256, 0, stream>>>(agg, feat, Wl2, Wr2, b2, feat);

    // layer 3
    gather_kernel<<<GATHER_BLOCKS, 256, 0, stream>>>(feat, offpk, csr, agg);
    layer_kernel<<<LAYER_BLOCKS, 256, 0, stream>>>(agg, feat, Wl3, Wr3, b3, feat);

    // head
    final_kernel<<<FINAL_BLOCKS, 256, 0, stream>>>(feat, Wlin, blin, out);
}

// Round 7
// 453.130 us; speedup vs baseline: 2.9426x; 1.0446x over previous
//
#include <hip/hip_runtime.h>
#include <hip/hip_bf16.h>

#define N_NODES 100000
#define N_EDGES 1600000
#define HID 64
#define OUT_CH 32

// Deterministic radix partition into dst buckets. Zero global atomics
// (R5: contended global cursors serialize device-wide at ~6 ns/atomic).
#define NB 196          // ceil(100000/512) buckets of 512 consecutive dst nodes
#define P 512           // partition blocks
#define EPP ((N_EDGES + P - 1) / P)   // 3125 edges per block
#define BKCAP 10240     // LDS csr staging cap (bucket mean 8192, sigma ~90)

// ---- edge_index dtype probe: int64 => all odd 32-bit words are 0 -----------
__global__ void detect_kernel(const int* __restrict__ ei, int* __restrict__ flag) {
    int i = threadIdx.x;  // 0..63
    int v = ei[2 * i + 1];
    unsigned long long ball = __ballot(v == 0);
    if (i == 0) *flag = (ball == ~0ull) ? 1 : 0;  // 1 = int64, 0 = int32
}

__device__ __forceinline__ int get_dst(const int* __restrict__ ei, int is64, int e) {
    return is64 ? ((const int2*)ei)[N_EDGES + e].x : ei[N_EDGES + e];
}
__device__ __forceinline__ int get_src(const int* __restrict__ ei, int is64, int e) {
    return is64 ? ((const int2*)ei)[e].x : ei[e];
}

// ---- pass 1: per-block bucket histograms ----------------------------------
__global__ void __launch_bounds__(256) hist_kernel(
        const int* __restrict__ ei, const int* __restrict__ flag,
        int* __restrict__ histG) {
    __shared__ int lh[NB];
    int tid = threadIdx.x;
    for (int i = tid; i < NB; i += 256) lh[i] = 0;
    __syncthreads();
    int is64 = *flag;
    int e0 = blockIdx.x * EPP;
    int e1 = min(e0 + EPP, N_EDGES);
    for (int e = e0 + tid; e < e1; e += 256) {
        int d = get_dst(ei, is64, e);
        atomicAdd(&lh[d >> 9], 1);
    }
    __syncthreads();
    for (int i = tid; i < NB; i += 256) histG[i * P + blockIdx.x] = lh[i];
}

// ---- per-bucket exclusive scan over P block-counts; emit bucket totals ----
__global__ void __launch_bounds__(256) scan_kernel(int* __restrict__ histG,
                                                   int* __restrict__ btot) {
    __shared__ int ps[256];
    int b = blockIdx.x;
    int tid = threadIdx.x;
    int v0 = histG[b * P + 2 * tid];
    int v1 = histG[b * P + 2 * tid + 1];
    int pv = v0 + v1;
    ps[tid] = pv;
    __syncthreads();
    for (int d = 1; d < 256; d <<= 1) {
        int t = (tid >= d) ? ps[tid - d] : 0;
        __syncthreads();
        ps[tid] += t;
        __syncthreads();
    }
    int excl = ps[tid] - pv;
    histG[b * P + 2 * tid] = excl;
    histG[b * P + 2 * tid + 1] = excl + v0;
    if (tid == 255) btot[b] = ps[255];
}

// ---- exclusive scan of 196 bucket totals -> dense bucket bases ------------
__global__ void base_scan_kernel(const int* __restrict__ btot, int* __restrict__ bbase) {
    __shared__ int s[256];
    int tid = threadIdx.x;
    int v = (tid < NB) ? btot[tid] : 0;
    s[tid] = v;
    __syncthreads();
    for (int d = 1; d < 256; d <<= 1) {
        int t = (tid >= d) ? s[tid - d] : 0;
        __syncthreads();
        s[tid] += t;
        __syncthreads();
    }
    if (tid < NB) bbase[tid] = s[tid] - v;
}

// ---- pass 2: place records at deterministic offsets (LDS cursors only) ----
// record = (dst&511)<<17 | src   (src < 2^17)
__global__ void __launch_bounds__(256) place_kernel(
        const int* __restrict__ ei, const int* __restrict__ flag,
        const int* __restrict__ histG, const int* __restrict__ bbase,
        int* __restrict__ bkt) {
    __shared__ int lcur[NB];
    int tid = threadIdx.x;
    for (int i = tid; i < NB; i += 256)
        lcur[i] = bbase[i] + histG[i * P + blockIdx.x];
    __syncthreads();
    int is64 = *flag;
    int e0 = blockIdx.x * EPP;
    int e1 = min(e0 + EPP, N_EDGES);
    for (int e = e0 + tid; e < e1; e += 256) {
        int s = get_src(ei, is64, e);
        int d = get_dst(ei, is64, e);
        int val = ((d & 511) << 17) | s;
        int p = atomicAdd(&lcur[d >> 9], 1);
        bkt[p] = val;
    }
}

// ---- per-bucket csr build in LDS + packed off|deg -------------------------
// offpk[n] = (abs_off & 0x1FFFFF) | (deg << 21);  off < 1.6M < 2^21, deg < 2048
__global__ void __launch_bounds__(256) bucket_fill_kernel(
        const int* __restrict__ bbase, const int* __restrict__ btot,
        const int* __restrict__ bkt, int* __restrict__ csr,
        unsigned int* __restrict__ offpk) {
    __shared__ int lcnt[512];
    __shared__ int loff[512];
    __shared__ int lcur[512];
    __shared__ int ps[256];
    __shared__ int scsr[BKCAP];
    int b = blockIdx.x;
    int tid = threadIdx.x;
    int base = bbase[b];
    int m = btot[b];
    int n0 = b << 9;
    int nn = min(512, N_NODES - n0);

    lcnt[tid] = 0;
    lcnt[tid + 256] = 0;
    __syncthreads();
    for (int i = tid; i < m; i += 256) atomicAdd(&lcnt[bkt[base + i] >> 17], 1);
    __syncthreads();
    int a0 = lcnt[2 * tid], a1 = lcnt[2 * tid + 1];
    int pv = a0 + a1;
    ps[tid] = pv;
    __syncthreads();
    for (int d = 1; d < 256; d <<= 1) {
        int t = (tid >= d) ? ps[tid - d] : 0;
        __syncthreads();
        ps[tid] += t;
        __syncthreads();
    }
    int excl = ps[tid] - pv;
    loff[2 * tid] = excl;
    loff[2 * tid + 1] = excl + a0;
    lcur[2 * tid] = excl;
    lcur[2 * tid + 1] = excl + a0;
    __syncthreads();
    bool fit = (m <= BKCAP);  // always true (mean 8192 + 22 sigma < BKCAP)
    for (int i = tid; i < m; i += 256) {
        int val = bkt[base + i];
        int dl = val >> 17;
        int p = atomicAdd(&lcur[dl], 1);
        if (fit) scsr[p] = val & 0x1FFFF;
        else csr[base + p] = val & 0x1FFFF;
    }
    __syncthreads();
    if (fit)
        for (int i = tid; i < m; i += 256) csr[base + i] = scsr[i];
    for (int i = tid; i < nn; i += 256)
        offpk[n0 + i] = (unsigned int)((base + loff[i]) | (lcnt[i] << 21));
}

// ---- gather-aggregate: one wave per node, lane = channel ------------------
// Indices loaded cooperatively (lane i gets csr[off0+i], one coalesced load
// per 64 edges) and distributed via __shfl; 8-deep unroll keeps 8 row loads
// in flight per wave to hide L2-miss/LLC latency.
__global__ void __launch_bounds__(256) gather_kernel(
        const float* __restrict__ h, const unsigned int* __restrict__ offpk,
        const int* __restrict__ csr, float* __restrict__ agg) {
    int node = blockIdx.x * 4 + (threadIdx.x >> 6);
    if (node >= N_NODES) return;
    int o = threadIdx.x & 63;
    unsigned int v = offpk[node];
    int off0 = (int)(v & 0x1FFFFFu);
    int cnt = (int)(v >> 21);
    const float* hro = h + o;
    float acc0 = 0.f, acc1 = 0.f;
    int base = off0;
    int rem = cnt;
    while (rem > 0) {
        int take = min(rem, 64);
        int idxv = (o < take) ? csr[base + o] : 0;
        int j = 0;
        for (; j + 8 <= take; j += 8) {
            int s0 = __shfl(idxv, j + 0);
            int s1 = __shfl(idxv, j + 1);
            int s2 = __shfl(idxv, j + 2);
            int s3 = __shfl(idxv, j + 3);
            int s4 = __shfl(idxv, j + 4);
            int s5 = __shfl(idxv, j + 5);
            int s6 = __shfl(idxv, j + 6);
            int s7 = __shfl(idxv, j + 7);
            float v0 = hro[(size_t)s0 * HID];
            float v1 = hro[(size_t)s1 * HID];
            float v2 = hro[(size_t)s2 * HID];
            float v3 = hro[(size_t)s3 * HID];
            float v4 = hro[(size_t)s4 * HID];
            float v5 = hro[(size_t)s5 * HID];
            float v6 = hro[(size_t)s6 * HID];
            float v7 = hro[(size_t)s7 * HID];
            acc0 += v0 + v1 + v2 + v3;
            acc1 += v4 + v5 + v6 + v7;
        }
        for (; j < take; ++j) acc0 += hro[(size_t)__shfl(idxv, j) * HID];
        base += take;
        rem -= take;
    }
    float inv = 1.f / fmaxf((float)cnt, 1.f);
    agg[(size_t)node * HID + o] = (acc0 + acc1) * inv;
}

// ---- layer GEMM: out = relu(agg@Wl + h@Wr + b), 64-node LDS tile ----------
#define LT 68
__global__ void __launch_bounds__(256) layer_kernel(
        const float* __restrict__ agg, const float* __restrict__ h,
        const float* __restrict__ Wl, const float* __restrict__ Wr,
        const float* __restrict__ bias, float* __restrict__ out) {
    __shared__ float sWl[HID * HID];
    __shared__ float sWr[HID * HID];
    __shared__ float sAT[HID * LT];
    __shared__ float sHT[HID * LT];
    __shared__ float sb[HID];
    int tid = threadIdx.x;
    {   // vectorized weight staging: float4 loads + stores
        const float4* Wl4 = (const float4*)Wl;
        const float4* Wr4 = (const float4*)Wr;
        float4* sWl4 = (float4*)sWl;
        float4* sWr4 = (float4*)sWr;
        for (int i = tid; i < HID * HID / 4; i += 256) {
            sWl4[i] = Wl4[i];
            sWr4[i] = Wr4[i];
        }
    }
    if (tid < HID) sb[tid] = bias[tid];

    int node0 = blockIdx.x * 64;
    int rr = tid >> 4;           // 0..15
    int cc = (tid & 15) << 2;    // 0,4,...,60
#pragma unroll
    for (int p = 0; p < 4; ++p) {
        int r = rr + p * 16;
        int n = node0 + r;
        float4 a, hh;
        if (n < N_NODES) {
            a = *(const float4*)(agg + (size_t)n * HID + cc);
            hh = *(const float4*)(h + (size_t)n * HID + cc);
        } else {
            a = make_float4(0, 0, 0, 0);
            hh = make_float4(0, 0, 0, 0);
        }
        sAT[(cc + 0) * LT + r] = a.x;  sAT[(cc + 1) * LT + r] = a.y;
        sAT[(cc + 2) * LT + r] = a.z;  sAT[(cc + 3) * LT + r] = a.w;
        sHT[(cc + 0) * LT + r] = hh.x; sHT[(cc + 1) * LT + r] = hh.y;
        sHT[(cc + 2) * LT + r] = hh.z; sHT[(cc + 3) * LT + r] = hh.w;
    }
    __syncthreads();

    int c0 = (tid & 15) << 2;
    int n0 = (tid >> 4) << 2;
    float acc[4][4];
#pragma unroll
    for (int i = 0; i < 4; ++i)
#pragma unroll
        for (int j = 0; j < 4; ++j) acc[i][j] = sb[c0 + j];

#pragma unroll 8
    for (int k = 0; k < HID; ++k) {
        float4 wl = *(const float4*)&sWl[k * HID + c0];
        float4 wr = *(const float4*)&sWr[k * HID + c0];
        float4 a4 = *(const float4*)&sAT[k * LT + n0];
        float4 h4 = *(const float4*)&sHT[k * LT + n0];
        const float* ap = (const float*)&a4;
        const float* hp = (const float*)&h4;
        const float* wlp = (const float*)&wl;
        const float* wrp = (const float*)&wr;
#pragma unroll
        for (int i = 0; i < 4; ++i)
#pragma unroll
            for (int j = 0; j < 4; ++j)
                acc[i][j] += ap[i] * wlp[j] + hp[i] * wrp[j];
    }

#pragma unroll
    for (int i = 0; i < 4; ++i) {
        int n = node0 + n0 + i;
        if (n < N_NODES) {
            float4 o4;
            o4.x = fmaxf(acc[i][0], 0.f);
            o4.y = fmaxf(acc[i][1], 0.f);
            o4.z = fmaxf(acc[i][2], 0.f);
            o4.w = fmaxf(acc[i][3], 0.f);
            *(float4*)(out + (size_t)n * HID + c0) = o4;
        }
    }
}

// ---- final head: out = h @ Wlin + blin (fp32 out) -------------------------
__global__ void __launch_bounds__(256) final_kernel(
        const float* __restrict__ h, const float* __restrict__ W,
        const float* __restrict__ b, float* __restrict__ out) {
    __shared__ float sW[HID * OUT_CH];
    __shared__ float sb[OUT_CH];
    int tid = threadIdx.x;
    {
        const float4* W4 = (const float4*)W;
        float4* sW4 = (float4*)sW;
        for (int i = tid; i < HID * OUT_CH / 4; i += 256) sW4[i] = W4[i];
    }
    if (tid < OUT_CH) sb[tid] = b[tid];
    __syncthreads();

    int node = blockIdx.x * 8 + (tid >> 5);
    if (node >= N_NODES) return;
    int o = tid & 31;
    const float* hr = h + (size_t)node * HID;
    float acc = sb[o];
#pragma unroll 8
    for (int k = 0; k < HID; k++) acc += hr[k] * sW[k * OUT_CH + o];
    out[(size_t)node * OUT_CH + o] = acc;
}

extern "C" void kernel_launch(void* const* d_in, const int* in_sizes, int n_in,
                              void* d_out, int out_size, void* d_ws, size_t ws_size,
                              hipStream_t stream) {
    const float* x    = (const float*)d_in[0];
    const int*   ei   = (const int*)d_in[1];
    const float* Wl1  = (const float*)d_in[2];
    const float* Wr1  = (const float*)d_in[3];
    const float* b1   = (const float*)d_in[4];
    const float* Wl2  = (const float*)d_in[5];
    const float* Wr2  = (const float*)d_in[6];
    const float* b2   = (const float*)d_in[7];
    const float* Wl3  = (const float*)d_in[8];
    const float* Wr3  = (const float*)d_in[9];
    const float* b3   = (const float*)d_in[10];
    const float* Wlin = (const float*)d_in[11];
    const float* blin = (const float*)d_in[12];
    float* out = (float*)d_out;

    // workspace layout (4-byte elements), ~58.6 MB total
    int* ip              = (int*)d_ws;
    int* flag            = ip;                          // 128
    unsigned int* offpk  = (unsigned int*)(flag + 128); // 100096
    int* bbase           = (int*)(offpk + 100096);      // 256
    int* btot            = bbase + 256;                 // 256
    int* histG           = btot + 256;                  // NB*P = 100352
    int* csr             = histG + NB * P;              // 1600000 (dense)
    float* agg           = (float*)(csr + N_EDGES);     // 6.4M floats
    float* feat          = agg + (size_t)N_NODES * HID; // 6.4M floats
    int* bkt             = (int*)agg;  // bucket records alias agg (dead until gather)

    const int GATHER_BLOCKS = (N_NODES + 3) / 4; // 25000
    const int LAYER_BLOCKS = (N_NODES + 63) / 64;// 1563
    const int FINAL_BLOCKS = (N_NODES + 7) / 8;  // 12500

    // CSR build: deterministic radix partition + per-bucket LDS fill
    detect_kernel<<<1, 64, 0, stream>>>(ei, flag);
    hist_kernel<<<P, 256, 0, stream>>>(ei, flag, histG);
    scan_kernel<<<NB, 256, 0, stream>>>(histG, btot);
    base_scan_kernel<<<1, 256, 0, stream>>>(btot, bbase);
    place_kernel<<<P, 256, 0, stream>>>(ei, flag, histG, bbase, bkt);
    bucket_fill_kernel<<<NB, 256, 0, stream>>>(bbase, btot, bkt, csr, offpk);

    // layer 1: x -> feat
    gather_kernel<<<GATHER_BLOCKS, 256, 0, stream>>>(x, offpk, csr, agg);
    layer_kernel<<<LAYER_BLOCKS, 256, 0, stream>>>(agg, x, Wl1, Wr1, b1, feat);

    // layer 2: feat -> feat (in-place safe: tile staged in LDS before write)
    gather_kernel<<<GATHER_BLOCKS, 256, 0, stream>>>(feat, offpk, csr, agg);
    layer_kernel<<<LAYER_BLOCKS, 256, 0, stream>>>(agg, feat, Wl2, Wr2, b2, feat);

    // layer 3
    gather_kernel<<<GATHER_BLOCKS, 256, 0, stream>>>(feat, offpk, csr, agg);
    layer_kernel<<<LAYER_BLOCKS, 256, 0, stream>>>(agg, feat, Wl3, Wr3, b3, feat);

    // head
    final_kernel<<<FINAL_BLOCKS, 256, 0, stream>>>(feat, Wlin, blin, out);
}

// Round 8
// 422.001 us; speedup vs baseline: 3.1597x; 1.0738x over previous
//
#include <hip/hip_runtime.h>
#include <hip/hip_bf16.h>

#define N_NODES 100000
#define N_EDGES 1600000
#define HID 64
#define OUT_CH 32

// Deterministic radix partition into dst buckets. Zero global atomics
// (R5: contended global cursors serialize device-wide at ~6 ns/atomic).
#define NB 196          // ceil(100000/512) buckets of 512 consecutive dst nodes
#define P 512           // partition blocks
#define EPP ((N_EDGES + P - 1) / P)   // 3125 edges per block
#define BKCAP 10240     // LDS csr staging cap (bucket mean 8192, sigma ~90)

typedef unsigned short ushort_t;

// bf16 helpers (RNE), independent of __hip_bfloat16 internals
__device__ __forceinline__ ushort_t f2b(float f) {
    union { float f; unsigned u; } un; un.f = f;
    unsigned r = un.u + 0x7FFF + ((un.u >> 16) & 1);
    return (ushort_t)(r >> 16);
}
__device__ __forceinline__ float b2f(ushort_t u) {
    union { unsigned u; float f; } un; un.u = ((unsigned)u) << 16;
    return un.f;
}
__device__ __forceinline__ float4 ld4(const float* p) { return *(const float4*)p; }
__device__ __forceinline__ float4 ld4(const ushort_t* p) {
    ushort4 u = *(const ushort4*)p;
    float4 f; f.x = b2f(u.x); f.y = b2f(u.y); f.z = b2f(u.z); f.w = b2f(u.w);
    return f;
}

// ---- edge_index dtype probe: int64 => all odd 32-bit words are 0 -----------
__global__ void detect_kernel(const int* __restrict__ ei, int* __restrict__ flag) {
    int i = threadIdx.x;  // 0..63
    int v = ei[2 * i + 1];
    unsigned long long ball = __ballot(v == 0);
    if (i == 0) *flag = (ball == ~0ull) ? 1 : 0;  // 1 = int64, 0 = int32
}

__device__ __forceinline__ int get_dst(const int* __restrict__ ei, int is64, int e) {
    return is64 ? ((const int2*)ei)[N_EDGES + e].x : ei[N_EDGES + e];
}
__device__ __forceinline__ int get_src(const int* __restrict__ ei, int is64, int e) {
    return is64 ? ((const int2*)ei)[e].x : ei[e];
}

// ---- convert x (fp32) -> bf16 feature buffer ------------------------------
__global__ void __launch_bounds__(256) convert_kernel(const float* __restrict__ x,
                                                      ushort_t* __restrict__ xb) {
    int i = blockIdx.x * 256 + threadIdx.x;   // one float4 per thread
    float4 v = ((const float4*)x)[i];
    ushort4 o;
    o.x = f2b(v.x); o.y = f2b(v.y); o.z = f2b(v.z); o.w = f2b(v.w);
    ((ushort4*)xb)[i] = o;
}

// ---- pass 1: per-block bucket histograms ----------------------------------
__global__ void __launch_bounds__(256) hist_kernel(
        const int* __restrict__ ei, const int* __restrict__ flag,
        int* __restrict__ histG) {
    __shared__ int lh[NB];
    int tid = threadIdx.x;
    for (int i = tid; i < NB; i += 256) lh[i] = 0;
    __syncthreads();
    int is64 = *flag;
    int e0 = blockIdx.x * EPP;
    int e1 = min(e0 + EPP, N_EDGES);
    for (int e = e0 + tid; e < e1; e += 256) {
        int d = get_dst(ei, is64, e);
        atomicAdd(&lh[d >> 9], 1);
    }
    __syncthreads();
    for (int i = tid; i < NB; i += 256) histG[i * P + blockIdx.x] = lh[i];
}

// ---- per-bucket exclusive scan over P block-counts; emit bucket totals ----
__global__ void __launch_bounds__(256) scan_kernel(int* __restrict__ histG,
                                                   int* __restrict__ btot) {
    __shared__ int ps[256];
    int b = blockIdx.x;
    int tid = threadIdx.x;
    int v0 = histG[b * P + 2 * tid];
    int v1 = histG[b * P + 2 * tid + 1];
    int pv = v0 + v1;
    ps[tid] = pv;
    __syncthreads();
    for (int d = 1; d < 256; d <<= 1) {
        int t = (tid >= d) ? ps[tid - d] : 0;
        __syncthreads();
        ps[tid] += t;
        __syncthreads();
    }
    int excl = ps[tid] - pv;
    histG[b * P + 2 * tid] = excl;
    histG[b * P + 2 * tid + 1] = excl + v0;
    if (tid == 255) btot[b] = ps[255];
}

// ---- exclusive scan of 196 bucket totals -> dense bucket bases ------------
__global__ void base_scan_kernel(const int* __restrict__ btot, int* __restrict__ bbase) {
    __shared__ int s[256];
    int tid = threadIdx.x;
    int v = (tid < NB) ? btot[tid] : 0;
    s[tid] = v;
    __syncthreads();
    for (int d = 1; d < 256; d <<= 1) {
        int t = (tid >= d) ? s[tid - d] : 0;
        __syncthreads();
        s[tid] += t;
        __syncthreads();
    }
    if (tid < NB) bbase[tid] = s[tid] - v;
}

// ---- pass 2: place records at deterministic offsets (LDS cursors only) ----
// record = (dst&511)<<17 | src   (src < 2^17)
__global__ void __launch_bounds__(256) place_kernel(
        const int* __restrict__ ei, const int* __restrict__ flag,
        const int* __restrict__ histG, const int* __restrict__ bbase,
        int* __restrict__ bkt) {
    __shared__ int lcur[NB];
    int tid = threadIdx.x;
    for (int i = tid; i < NB; i += 256)
        lcur[i] = bbase[i] + histG[i * P + blockIdx.x];
    __syncthreads();
    int is64 = *flag;
    int e0 = blockIdx.x * EPP;
    int e1 = min(e0 + EPP, N_EDGES);
    for (int e = e0 + tid; e < e1; e += 256) {
        int s = get_src(ei, is64, e);
        int d = get_dst(ei, is64, e);
        int val = ((d & 511) << 17) | s;
        int p = atomicAdd(&lcur[d >> 9], 1);
        bkt[p] = val;
    }
}

// ---- per-bucket csr build in LDS + packed off|deg -------------------------
// offpk[n] = (abs_off & 0x1FFFFF) | (deg << 21)
__global__ void __launch_bounds__(256) bucket_fill_kernel(
        const int* __restrict__ bbase, const int* __restrict__ btot,
        const int* __restrict__ bkt, int* __restrict__ csr,
        unsigned int* __restrict__ offpk) {
    __shared__ int lcnt[512];
    __shared__ int loff[512];
    __shared__ int lcur[512];
    __shared__ int ps[256];
    __shared__ int scsr[BKCAP];
    int b = blockIdx.x;
    int tid = threadIdx.x;
    int base = bbase[b];
    int m = btot[b];
    int n0 = b << 9;
    int nn = min(512, N_NODES - n0);

    lcnt[tid] = 0;
    lcnt[tid + 256] = 0;
    __syncthreads();
    for (int i = tid; i < m; i += 256) atomicAdd(&lcnt[bkt[base + i] >> 17], 1);
    __syncthreads();
    int a0 = lcnt[2 * tid], a1 = lcnt[2 * tid + 1];
    int pv = a0 + a1;
    ps[tid] = pv;
    __syncthreads();
    for (int d = 1; d < 256; d <<= 1) {
        int t = (tid >= d) ? ps[tid - d] : 0;
        __syncthreads();
        ps[tid] += t;
        __syncthreads();
    }
    int excl = ps[tid] - pv;
    loff[2 * tid] = excl;
    loff[2 * tid + 1] = excl + a0;
    lcur[2 * tid] = excl;
    lcur[2 * tid + 1] = excl + a0;
    __syncthreads();
    bool fit = (m <= BKCAP);  // always true (mean 8192 + 22 sigma < BKCAP)
    for (int i = tid; i < m; i += 256) {
        int val = bkt[base + i];
        int dl = val >> 17;
        int p = atomicAdd(&lcur[dl], 1);
        if (fit) scsr[p] = val & 0x1FFFF;
        else csr[base + p] = val & 0x1FFFF;
    }
    __syncthreads();
    if (fit)
        for (int i = tid; i < m; i += 256) csr[base + i] = scsr[i];
    for (int i = tid; i < nn; i += 256)
        offpk[n0 + i] = (unsigned int)((base + loff[i]) | (lcnt[i] << 21));
}

// ---- gather-aggregate from bf16 rows: one wave per node, lane = channel ---
// Cooperative index loads + 16-deep unroll for MLP; accumulate fp32.
__global__ void __launch_bounds__(256) gather_kernel(
        const ushort_t* __restrict__ hb, const unsigned int* __restrict__ offpk,
        const int* __restrict__ csr, float* __restrict__ agg) {
    int node = blockIdx.x * 4 + (threadIdx.x >> 6);
    if (node >= N_NODES) return;
    int o = threadIdx.x & 63;
    unsigned int v = offpk[node];
    int off0 = (int)(v & 0x1FFFFFu);
    int cnt = (int)(v >> 21);
    const ushort_t* hro = hb + o;
    float acc0 = 0.f, acc1 = 0.f;
    int base = off0;
    int rem = cnt;
    while (rem > 0) {
        int take = min(rem, 64);
        int idxv = (o < take) ? csr[base + o] : 0;
        int j = 0;
        for (; j + 16 <= take; j += 16) {
            int s0 = __shfl(idxv, j + 0),  s1 = __shfl(idxv, j + 1);
            int s2 = __shfl(idxv, j + 2),  s3 = __shfl(idxv, j + 3);
            int s4 = __shfl(idxv, j + 4),  s5 = __shfl(idxv, j + 5);
            int s6 = __shfl(idxv, j + 6),  s7 = __shfl(idxv, j + 7);
            int s8 = __shfl(idxv, j + 8),  s9 = __shfl(idxv, j + 9);
            int sa = __shfl(idxv, j + 10), sb = __shfl(idxv, j + 11);
            int sc = __shfl(idxv, j + 12), sd = __shfl(idxv, j + 13);
            int se = __shfl(idxv, j + 14), sf = __shfl(idxv, j + 15);
            float v0 = b2f(hro[(size_t)s0 * HID]), v1 = b2f(hro[(size_t)s1 * HID]);
            float v2 = b2f(hro[(size_t)s2 * HID]), v3 = b2f(hro[(size_t)s3 * HID]);
            float v4 = b2f(hro[(size_t)s4 * HID]), v5 = b2f(hro[(size_t)s5 * HID]);
            float v6 = b2f(hro[(size_t)s6 * HID]), v7 = b2f(hro[(size_t)s7 * HID]);
            float v8 = b2f(hro[(size_t)s8 * HID]), v9 = b2f(hro[(size_t)s9 * HID]);
            float va = b2f(hro[(size_t)sa * HID]), vb = b2f(hro[(size_t)sb * HID]);
            float vc = b2f(hro[(size_t)sc * HID]), vd = b2f(hro[(size_t)sd * HID]);
            float ve = b2f(hro[(size_t)se * HID]), vf = b2f(hro[(size_t)sf * HID]);
            acc0 += ((v0 + v1) + (v2 + v3)) + ((v4 + v5) + (v6 + v7));
            acc1 += ((v8 + v9) + (va + vb)) + ((vc + vd) + (ve + vf));
        }
        for (; j + 4 <= take; j += 4) {
            int s0 = __shfl(idxv, j + 0), s1 = __shfl(idxv, j + 1);
            int s2 = __shfl(idxv, j + 2), s3 = __shfl(idxv, j + 3);
            float v0 = b2f(hro[(size_t)s0 * HID]), v1 = b2f(hro[(size_t)s1 * HID]);
            float v2 = b2f(hro[(size_t)s2 * HID]), v3 = b2f(hro[(size_t)s3 * HID]);
            acc0 += (v0 + v1) + (v2 + v3);
        }
        for (; j < take; ++j) acc1 += b2f(hro[(size_t)__shfl(idxv, j) * HID]);
        base += take;
        rem -= take;
    }
    float inv = 1.f / fmaxf((float)cnt, 1.f);
    agg[(size_t)node * HID + o] = (acc0 + acc1) * inv;
}

// ---- layer GEMM: relu(agg@Wl + h@Wr + b) -> bf16 feat ---------------------
#define LT 68
template <typename RT>
__global__ void __launch_bounds__(256) layer_kernel(
        const float* __restrict__ agg, const RT* __restrict__ h,
        const float* __restrict__ Wl, const float* __restrict__ Wr,
        const float* __restrict__ bias, ushort_t* __restrict__ outb) {
    __shared__ float sWl[HID * HID];
    __shared__ float sWr[HID * HID];
    __shared__ float sAT[HID * LT];
    __shared__ float sHT[HID * LT];
    __shared__ float sb[HID];
    int tid = threadIdx.x;
    {
        const float4* Wl4 = (const float4*)Wl;
        const float4* Wr4 = (const float4*)Wr;
        float4* sWl4 = (float4*)sWl;
        float4* sWr4 = (float4*)sWr;
        for (int i = tid; i < HID * HID / 4; i += 256) {
            sWl4[i] = Wl4[i];
            sWr4[i] = Wr4[i];
        }
    }
    if (tid < HID) sb[tid] = bias[tid];

    int node0 = blockIdx.x * 64;
    int rr = tid >> 4;
    int cc = (tid & 15) << 2;
#pragma unroll
    for (int p = 0; p < 4; ++p) {
        int r = rr + p * 16;
        int n = node0 + r;
        float4 a = make_float4(0, 0, 0, 0), hh = make_float4(0, 0, 0, 0);
        if (n < N_NODES) {
            a = ld4(agg + (size_t)n * HID + cc);
            hh = ld4(h + (size_t)n * HID + cc);
        }
        sAT[(cc + 0) * LT + r] = a.x;  sAT[(cc + 1) * LT + r] = a.y;
        sAT[(cc + 2) * LT + r] = a.z;  sAT[(cc + 3) * LT + r] = a.w;
        sHT[(cc + 0) * LT + r] = hh.x; sHT[(cc + 1) * LT + r] = hh.y;
        sHT[(cc + 2) * LT + r] = hh.z; sHT[(cc + 3) * LT + r] = hh.w;
    }
    __syncthreads();

    int c0 = (tid & 15) << 2;
    int n0 = (tid >> 4) << 2;
    float acc[4][4];
#pragma unroll
    for (int i = 0; i < 4; ++i)
#pragma unroll
        for (int j = 0; j < 4; ++j) acc[i][j] = sb[c0 + j];

#pragma unroll 8
    for (int k = 0; k < HID; ++k) {
        float4 wl = *(const float4*)&sWl[k * HID + c0];
        float4 wr = *(const float4*)&sWr[k * HID + c0];
        float4 a4 = *(const float4*)&sAT[k * LT + n0];
        float4 h4 = *(const float4*)&sHT[k * LT + n0];
        const float* ap = (const float*)&a4;
        const float* hp = (const float*)&h4;
        const float* wlp = (const float*)&wl;
        const float* wrp = (const float*)&wr;
#pragma unroll
        for (int i = 0; i < 4; ++i)
#pragma unroll
            for (int j = 0; j < 4; ++j)
                acc[i][j] += ap[i] * wlp[j] + hp[i] * wrp[j];
    }

#pragma unroll
    for (int i = 0; i < 4; ++i) {
        int n = node0 + n0 + i;
        if (n < N_NODES) {
            ushort4 w;
            w.x = f2b(fmaxf(acc[i][0], 0.f));
            w.y = f2b(fmaxf(acc[i][1], 0.f));
            w.z = f2b(fmaxf(acc[i][2], 0.f));
            w.w = f2b(fmaxf(acc[i][3], 0.f));
            *(ushort4*)(outb + (size_t)n * HID + c0) = w;
        }
    }
}

// ---- fused layer3 + head: out = relu(agg@Wl3 + h@Wr3 + b3) @ Wlin + blin --
__global__ void __launch_bounds__(256) layer3_head_kernel(
        const float* __restrict__ agg, const ushort_t* __restrict__ h,
        const float* __restrict__ Wl, const float* __restrict__ Wr,
        const float* __restrict__ bias, const float* __restrict__ Wlin,
        const float* __restrict__ blin, float* __restrict__ out) {
    __shared__ float sWl[HID * HID];
    __shared__ float sWr[HID * HID];
    __shared__ float sAT[HID * LT];    // reused as sH3[64][65] after GEMM1
    __shared__ float sHT[HID * LT];
    __shared__ float sWo[HID * OUT_CH];
    __shared__ float sb[HID];
    __shared__ float sb2[OUT_CH];
    int tid = threadIdx.x;
    {
        const float4* Wl4 = (const float4*)Wl;
        const float4* Wr4 = (const float4*)Wr;
        const float4* Wo4 = (const float4*)Wlin;
        float4* sWl4 = (float4*)sWl;
        float4* sWr4 = (float4*)sWr;
        float4* sWo4 = (float4*)sWo;
        for (int i = tid; i < HID * HID / 4; i += 256) {
            sWl4[i] = Wl4[i];
            sWr4[i] = Wr4[i];
        }
        for (int i = tid; i < HID * OUT_CH / 4; i += 256) sWo4[i] = Wo4[i];
    }
    if (tid < HID) sb[tid] = bias[tid];
    if (tid < OUT_CH) sb2[tid] = blin[tid];

    int node0 = blockIdx.x * 64;
    int rr = tid >> 4;
    int cc = (tid & 15) << 2;
#pragma unroll
    for (int p = 0; p < 4; ++p) {
        int r = rr + p * 16;
        int n = node0 + r;
        float4 a = make_float4(0, 0, 0, 0), hh = make_float4(0, 0, 0, 0);
        if (n < N_NODES) {
            a = ld4(agg + (size_t)n * HID + cc);
            hh = ld4(h + (size_t)n * HID + cc);
        }
        sAT[(cc + 0) * LT + r] = a.x;  sAT[(cc + 1) * LT + r] = a.y;
        sAT[(cc + 2) * LT + r] = a.z;  sAT[(cc + 3) * LT + r] = a.w;
        sHT[(cc + 0) * LT + r] = hh.x; sHT[(cc + 1) * LT + r] = hh.y;
        sHT[(cc + 2) * LT + r] = hh.z; sHT[(cc + 3) * LT + r] = hh.w;
    }
    __syncthreads();

    int c0 = (tid & 15) << 2;
    int n0 = (tid >> 4) << 2;
    float acc[4][4];
#pragma unroll
    for (int i = 0; i < 4; ++i)
#pragma unroll
        for (int j = 0; j < 4; ++j) acc[i][j] = sb[c0 + j];

#pragma unroll 8
    for (int k = 0; k < HID; ++k) {
        float4 wl = *(const float4*)&sWl[k * HID + c0];
        float4 wr = *(const float4*)&sWr[k * HID + c0];
        float4 a4 = *(const float4*)&sAT[k * LT + n0];
        float4 h4 = *(const float4*)&sHT[k * LT + n0];
        const float* ap = (const float*)&a4;
        const float* hp = (const float*)&h4;
        const float* wlp = (const float*)&wl;
        const float* wrp = (const float*)&wr;
#pragma unroll
        for (int i = 0; i < 4; ++i)
#pragma unroll
            for (int j = 0; j < 4; ++j)
                acc[i][j] += ap[i] * wlp[j] + hp[i] * wrp[j];
    }
    __syncthreads();  // all GEMM1 reads of sAT done

    // write relu(h3) tile into sAT as [n][k], pad 65
    float* sH3 = sAT;
#pragma unroll
    for (int i = 0; i < 4; ++i)
#pragma unroll
        for (int j = 0; j < 4; ++j)
            sH3[(n0 + i) * 65 + c0 + j] = fmaxf(acc[i][j], 0.f);
    __syncthreads();

    // GEMM2: out[n][o] = blin[o] + sum_k sH3[n][k] * Wlin[k][o]
    int o = tid & 31;
    int r2 = tid >> 5;  // 0..7
#pragma unroll
    for (int p = 0; p < 8; ++p) {
        int n = p * 8 + r2;
        int gn = node0 + n;
        if (gn >= N_NODES) break;
        float a2 = sb2[o];
#pragma unroll 8
        for (int k = 0; k < HID; ++k) a2 += sH3[n * 65 + k] * sWo[k * OUT_CH + o];
        out[(size_t)gn * OUT_CH + o] = a2;
    }
}

extern "C" void kernel_launch(void* const* d_in, const int* in_sizes, int n_in,
                              void* d_out, int out_size, void* d_ws, size_t ws_size,
                              hipStream_t stream) {
    const float* x    = (const float*)d_in[0];
    const int*   ei   = (const int*)d_in[1];
    const float* Wl1  = (const float*)d_in[2];
    const float* Wr1  = (const float*)d_in[3];
    const float* b1   = (const float*)d_in[4];
    const float* Wl2  = (const float*)d_in[5];
    const float* Wr2  = (const float*)d_in[6];
    const float* b2   = (const float*)d_in[7];
    const float* Wl3  = (const float*)d_in[8];
    const float* Wr3  = (const float*)d_in[9];
    const float* b3   = (const float*)d_in[10];
    const float* Wlin = (const float*)d_in[11];
    const float* blin = (const float*)d_in[12];
    float* out = (float*)d_out;

    // workspace layout (4-byte elements unless noted), ~45.6 MB total
    int* ip              = (int*)d_ws;
    int* flag            = ip;                          // 128
    unsigned int* offpk  = (unsigned int*)(flag + 128); // 100096
    int* bbase           = (int*)(offpk + 100096);      // 256
    int* btot            = bbase + 256;                 // 256
    int* histG           = btot + 256;                  // NB*P = 100352
    int* csr             = histG + NB * P;              // 1600000 (dense)
    float* agg           = (float*)(csr + N_EDGES);     // 6.4M floats
    ushort_t* featb      = (ushort_t*)(agg + (size_t)N_NODES * HID);  // 6.4M bf16
    int* bkt             = (int*)agg;  // bucket records alias agg (dead until gather)

    const int CONV_BLOCKS   = (N_NODES * HID / 4) / 256; // 6250
    const int GATHER_BLOCKS = (N_NODES + 3) / 4;         // 25000
    const int LAYER_BLOCKS  = (N_NODES + 63) / 64;       // 1563

    // x -> bf16, CSR build (deterministic radix partition + per-bucket fill)
    convert_kernel<<<CONV_BLOCKS, 256, 0, stream>>>(x, featb);
    detect_kernel<<<1, 64, 0, stream>>>(ei, flag);
    hist_kernel<<<P, 256, 0, stream>>>(ei, flag, histG);
    scan_kernel<<<NB, 256, 0, stream>>>(histG, btot);
    base_scan_kernel<<<1, 256, 0, stream>>>(btot, bbase);
    place_kernel<<<P, 256, 0, stream>>>(ei, flag, histG, bbase, bkt);
    bucket_fill_kernel<<<NB, 256, 0, stream>>>(bbase, btot, bkt, csr, offpk);

    // layer 1: featb(=bf16 x) -> agg; root from fp32 x; out bf16 featb
    gather_kernel<<<GATHER_BLOCKS, 256, 0, stream>>>(featb, offpk, csr, agg);
    layer_kernel<float><<<LAYER_BLOCKS, 256, 0, stream>>>(agg, x, Wl1, Wr1, b1, featb);

    // layer 2: featb -> agg; root featb; out featb (block-local in-place)
    gather_kernel<<<GATHER_BLOCKS, 256, 0, stream>>>(featb, offpk, csr, agg);
    layer_kernel<ushort_t><<<LAYER_BLOCKS, 256, 0, stream>>>(agg, featb, Wl2, Wr2, b2, featb);

    // layer 3 + head fused -> out
    gather_kernel<<<GATHER_BLOCKS, 256, 0, stream>>>(featb, offpk, csr, agg);
    layer3_head_kernel<<<LAYER_BLOCKS, 256, 0, stream>>>(agg, featb, Wl3, Wr3, b3,
                                                         Wlin, blin, out);
}

// Round 10
// 378.538 us; speedup vs baseline: 3.5225x; 1.1148x over previous
//
#include <hip/hip_runtime.h>
#include <hip/hip_bf16.h>

#define N_NODES 100000
#define N_EDGES 1600000
#define HID 64
#define OUT_CH 32

// Deterministic radix partition into dst buckets. Zero global atomics
// (R5: contended global cursors serialize device-wide at ~6 ns/atomic).
#define NB 196           // ceil(100000/512) buckets of 512 consecutive dst nodes
#define P 1024           // partition blocks
#define EPP ((N_EDGES + P - 1) / P)   // 1563 edges per block
#define BKCAP 10240      // LDS csr staging cap (bucket mean 8192, sigma ~90)
#define SAP 66           // bf16 tile pitch (+2 pad: conflict-free row reads)

typedef unsigned short ushort_t;

// bf16 helpers (RNE)
__device__ __forceinline__ ushort_t f2b(float f) {
    union { float f; unsigned u; } un; un.f = f;
    unsigned r = un.u + 0x7FFF + ((un.u >> 16) & 1);
    return (ushort_t)(r >> 16);
}
__device__ __forceinline__ float b2f(ushort_t u) {
    union { unsigned u; float f; } un; un.u = ((unsigned)u) << 16;
    return un.f;
}
__device__ __forceinline__ float blo(unsigned u) {
    union { unsigned u; float f; } un; un.u = u << 16; return un.f;
}
__device__ __forceinline__ float bhi(unsigned u) {
    union { unsigned u; float f; } un; un.u = u & 0xFFFF0000u; return un.f;
}

// ---- edge_index dtype probe: int64 => all odd 32-bit words are 0 -----------
__global__ void detect_kernel(const int* __restrict__ ei, int* __restrict__ flag) {
    int i = threadIdx.x;
    int v = ei[2 * i + 1];
    unsigned long long ball = __ballot(v == 0);
    if (i == 0) *flag = (ball == ~0ull) ? 1 : 0;
}
__device__ __forceinline__ int get_dst(const int* __restrict__ ei, int is64, int e) {
    return is64 ? ((const int2*)ei)[N_EDGES + e].x : ei[N_EDGES + e];
}
__device__ __forceinline__ int get_src(const int* __restrict__ ei, int is64, int e) {
    return is64 ? ((const int2*)ei)[e].x : ei[e];
}

// ---- convert x (fp32) -> bf16 feature buffer ------------------------------
__global__ void __launch_bounds__(256) convert_kernel(const float* __restrict__ x,
                                                      ushort_t* __restrict__ xb) {
    int i = blockIdx.x * 256 + threadIdx.x;
    float4 v = ((const float4*)x)[i];
    ushort4 o;
    o.x = f2b(v.x); o.y = f2b(v.y); o.z = f2b(v.z); o.w = f2b(v.w);
    ((ushort4*)xb)[i] = o;
}

// ---- pass 1: per-block bucket histograms ----------------------------------
__global__ void __launch_bounds__(256) hist_kernel(
        const int* __restrict__ ei, const int* __restrict__ flag,
        int* __restrict__ histG) {
    __shared__ int lh[NB];
    int tid = threadIdx.x;
    for (int i = tid; i < NB; i += 256) lh[i] = 0;
    __syncthreads();
    int is64 = *flag;
    int e0 = blockIdx.x * EPP;
    int e1 = min(e0 + EPP, N_EDGES);
    for (int e = e0 + tid; e < e1; e += 256) {
        int d = get_dst(ei, is64, e);
        atomicAdd(&lh[d >> 9], 1);
    }
    __syncthreads();
    for (int i = tid; i < NB; i += 256) histG[i * P + blockIdx.x] = lh[i];
}

// ---- per-bucket exclusive scan over P block-counts (4 elems/thread) -------
__global__ void __launch_bounds__(256) scan_kernel(int* __restrict__ histG,
                                                   int* __restrict__ btot) {
    __shared__ int ps[256];
    int b = blockIdx.x;
    int tid = threadIdx.x;
    int base4 = b * P + 4 * tid;
    int v0 = histG[base4], v1 = histG[base4 + 1], v2 = histG[base4 + 2], v3 = histG[base4 + 3];
    int pv = v0 + v1 + v2 + v3;
    ps[tid] = pv;
    __syncthreads();
    for (int d = 1; d < 256; d <<= 1) {
        int t = (tid >= d) ? ps[tid - d] : 0;
        __syncthreads();
        ps[tid] += t;
        __syncthreads();
    }
    int e = ps[tid] - pv;
    histG[base4] = e; e += v0;
    histG[base4 + 1] = e; e += v1;
    histG[base4 + 2] = e; e += v2;
    histG[base4 + 3] = e;
    if (tid == 255) btot[b] = ps[255];
}

// ---- exclusive scan of 196 bucket totals -> dense bucket bases ------------
__global__ void base_scan_kernel(const int* __restrict__ btot, int* __restrict__ bbase) {
    __shared__ int s[256];
    int tid = threadIdx.x;
    int v = (tid < NB) ? btot[tid] : 0;
    s[tid] = v;
    __syncthreads();
    for (int d = 1; d < 256; d <<= 1) {
        int t = (tid >= d) ? s[tid - d] : 0;
        __syncthreads();
        s[tid] += t;
        __syncthreads();
    }
    if (tid < NB) bbase[tid] = s[tid] - v;
}

// ---- pass 2: place records at deterministic offsets (LDS cursors only) ----
// record = (dst&511)<<17 | src
__global__ void __launch_bounds__(256) place_kernel(
        const int* __restrict__ ei, const int* __restrict__ flag,
        const int* __restrict__ histG, const int* __restrict__ bbase,
        int* __restrict__ bkt) {
    __shared__ int lcur[NB];
    int tid = threadIdx.x;
    for (int i = tid; i < NB; i += 256)
        lcur[i] = bbase[i] + histG[i * P + blockIdx.x];
    __syncthreads();
    int is64 = *flag;
    int e0 = blockIdx.x * EPP;
    int e1 = min(e0 + EPP, N_EDGES);
    for (int e = e0 + tid; e < e1; e += 256) {
        int s = get_src(ei, is64, e);
        int d = get_dst(ei, is64, e);
        int val = ((d & 511) << 17) | s;
        int p = atomicAdd(&lcur[d >> 9], 1);
        bkt[p] = val;
    }
}

// ---- per-bucket csr build in LDS + packed off|deg -------------------------
// offpk[n] = (abs_off & 0x1FFFFF) | (deg << 21)
__global__ void __launch_bounds__(256) bucket_fill_kernel(
        const int* __restrict__ bbase, const int* __restrict__ btot,
        const int* __restrict__ bkt, int* __restrict__ csr,
        unsigned int* __restrict__ offpk) {
    __shared__ int lcnt[512];
    __shared__ int loff[512];
    __shared__ int lcur[512];
    __shared__ int ps[256];
    __shared__ int scsr[BKCAP];
    int b = blockIdx.x;
    int tid = threadIdx.x;
    int base = bbase[b];
    int m = btot[b];
    int n0 = b << 9;
    int nn = min(512, N_NODES - n0);

    lcnt[tid] = 0;
    lcnt[tid + 256] = 0;
    __syncthreads();
    for (int i = tid; i < m; i += 256) atomicAdd(&lcnt[bkt[base + i] >> 17], 1);
    __syncthreads();
    int a0 = lcnt[2 * tid], a1 = lcnt[2 * tid + 1];
    int pv = a0 + a1;
    ps[tid] = pv;
    __syncthreads();
    for (int d = 1; d < 256; d <<= 1) {
        int t = (tid >= d) ? ps[tid - d] : 0;
        __syncthreads();
        ps[tid] += t;
        __syncthreads();
    }
    int excl = ps[tid] - pv;
    loff[2 * tid] = excl;
    loff[2 * tid + 1] = excl + a0;
    lcur[2 * tid] = excl;
    lcur[2 * tid + 1] = excl + a0;
    __syncthreads();
    bool fit = (m <= BKCAP);
    for (int i = tid; i < m; i += 256) {
        int val = bkt[base + i];
        int dl = val >> 17;
        int p = atomicAdd(&lcur[dl], 1);
        if (fit) scsr[p] = val & 0x1FFFF;
        else csr[base + p] = val & 0x1FFFF;
    }
    __syncthreads();
    if (fit)
        for (int i = tid; i < m; i += 256) csr[base + i] = scsr[i];
    for (int i = tid; i < nn; i += 256)
        offpk[n0 + i] = (unsigned int)((base + loff[i]) | (lcnt[i] << 21));
}

// ---- gather-aggregate bf16 rows -> bf16 agg; fp32 accumulate --------------
__global__ void __launch_bounds__(256) gather_kernel(
        const ushort_t* __restrict__ hb, const unsigned int* __restrict__ offpk,
        const int* __restrict__ csr, ushort_t* __restrict__ aggb) {
    int node = blockIdx.x * 4 + (threadIdx.x >> 6);
    if (node >= N_NODES) return;
    int o = threadIdx.x & 63;
    unsigned int v = offpk[node];
    int off0 = (int)(v & 0x1FFFFFu);
    int cnt = (int)(v >> 21);
    const ushort_t* hro = hb + o;
    float acc0 = 0.f, acc1 = 0.f;
    int base = off0;
    int rem = cnt;
    while (rem > 0) {
        int take = min(rem, 64);
        int idxv = (o < take) ? csr[base + o] : 0;
        int j = 0;
        for (; j + 16 <= take; j += 16) {
            int s0 = __shfl(idxv, j + 0),  s1 = __shfl(idxv, j + 1);
            int s2 = __shfl(idxv, j + 2),  s3 = __shfl(idxv, j + 3);
            int s4 = __shfl(idxv, j + 4),  s5 = __shfl(idxv, j + 5);
            int s6 = __shfl(idxv, j + 6),  s7 = __shfl(idxv, j + 7);
            int s8 = __shfl(idxv, j + 8),  s9 = __shfl(idxv, j + 9);
            int sa = __shfl(idxv, j + 10), sb = __shfl(idxv, j + 11);
            int sc = __shfl(idxv, j + 12), sd = __shfl(idxv, j + 13);
            int se = __shfl(idxv, j + 14), sf = __shfl(idxv, j + 15);
            float v0 = b2f(hro[(size_t)s0 * HID]), v1 = b2f(hro[(size_t)s1 * HID]);
            float v2 = b2f(hro[(size_t)s2 * HID]), v3 = b2f(hro[(size_t)s3 * HID]);
            float v4 = b2f(hro[(size_t)s4 * HID]), v5 = b2f(hro[(size_t)s5 * HID]);
            float v6 = b2f(hro[(size_t)s6 * HID]), v7 = b2f(hro[(size_t)s7 * HID]);
            float v8 = b2f(hro[(size_t)s8 * HID]), v9 = b2f(hro[(size_t)s9 * HID]);
            float va = b2f(hro[(size_t)sa * HID]), vb = b2f(hro[(size_t)sb * HID]);
            float vc = b2f(hro[(size_t)sc * HID]), vd = b2f(hro[(size_t)sd * HID]);
            float ve = b2f(hro[(size_t)se * HID]), vf = b2f(hro[(size_t)sf * HID]);
            acc0 += ((v0 + v1) + (v2 + v3)) + ((v4 + v5) + (v6 + v7));
            acc1 += ((v8 + v9) + (va + vb)) + ((vc + vd) + (ve + vf));
        }
        for (; j + 4 <= take; j += 4) {
            int s0 = __shfl(idxv, j + 0), s1 = __shfl(idxv, j + 1);
            int s2 = __shfl(idxv, j + 2), s3 = __shfl(idxv, j + 3);
            float v0 = b2f(hro[(size_t)s0 * HID]), v1 = b2f(hro[(size_t)s1 * HID]);
            float v2 = b2f(hro[(size_t)s2 * HID]), v3 = b2f(hro[(size_t)s3 * HID]);
            acc0 += (v0 + v1) + (v2 + v3);
        }
        for (; j < take; ++j) acc1 += b2f(hro[(size_t)__shfl(idxv, j) * HID]);
        base += take;
        rem -= take;
    }
    float inv = 1.f / fmaxf((float)cnt, 1.f);
    aggb[(size_t)node * HID + o] = f2b((acc0 + acc1) * inv);
}

// ---- layer v2: relu(agg@Wl + h@Wr + b) -> bf16, conflict-free LDS ---------
// bf16 tiles row-major pitch 66. 64x64 ushort tile = 4096 ushorts = 512 int4
// chunks => staging loop runs p<2 (R9 bug: p<4 overflowed sA by 2x -> LDS
// corruption, absmax 71).
__global__ void __launch_bounds__(256) layer_v2(
        const ushort_t* __restrict__ aggb, const ushort_t* __restrict__ rootb,
        const float* __restrict__ Wl, const float* __restrict__ Wr,
        const float* __restrict__ bias, ushort_t* outb) {
    __shared__ float sWl[HID * HID];
    __shared__ float sWr[HID * HID];
    __shared__ ushort_t sA[64 * SAP];
    __shared__ ushort_t sH[64 * SAP];
    __shared__ float sb[HID];
    int tid = threadIdx.x;
    {
        const float4* Wl4 = (const float4*)Wl;
        const float4* Wr4 = (const float4*)Wr;
        float4* sWl4 = (float4*)sWl;
        float4* sWr4 = (float4*)sWr;
        for (int i = tid; i < HID * HID / 4; i += 256) {
            sWl4[i] = Wl4[i];
            sWr4[i] = Wr4[i];
        }
    }
    if (tid < HID) sb[tid] = bias[tid];
    size_t tbase = (size_t)blockIdx.x * 64 * HID;   // ushort offset of tile
    {   // 512 chunks of 8 ushorts (16 B): 2 per thread
        const int4* ga = (const int4*)(aggb + tbase);
        const int4* gh = (const int4*)(rootb + tbase);
#pragma unroll
        for (int p = 0; p < 2; ++p) {
            int q = tid + 256 * p;          // chunk 0..511
            int r = q >> 3, u = q & 7;      // row 0..63, 8-ushort col group
            *(int4*)(sA + r * SAP + u * 8) = ga[q];
            *(int4*)(sH + r * SAP + u * 8) = gh[q];
        }
    }
    __syncthreads();

    int c0 = (tid & 15) << 2;
    int n0 = (tid >> 4) << 2;
    float acc[4][4];
#pragma unroll
    for (int i = 0; i < 4; ++i)
#pragma unroll
        for (int j = 0; j < 4; ++j) acc[i][j] = sb[c0 + j];

#pragma unroll 4
    for (int kk = 0; kk < 32; ++kk) {
        float4 wl0 = *(const float4*)&sWl[(2 * kk) * HID + c0];
        float4 wl1 = *(const float4*)&sWl[(2 * kk + 1) * HID + c0];
        float4 wr0 = *(const float4*)&sWr[(2 * kk) * HID + c0];
        float4 wr1 = *(const float4*)&sWr[(2 * kk + 1) * HID + c0];
        const float* wl0p = (const float*)&wl0;
        const float* wl1p = (const float*)&wl1;
        const float* wr0p = (const float*)&wr0;
        const float* wr1p = (const float*)&wr1;
#pragma unroll
        for (int i = 0; i < 4; ++i) {
            unsigned ua = *(const unsigned*)(sA + (n0 + i) * SAP + 2 * kk);
            unsigned uh = *(const unsigned*)(sH + (n0 + i) * SAP + 2 * kk);
            float a0 = blo(ua), a1 = bhi(ua);
            float h0 = blo(uh), h1 = bhi(uh);
#pragma unroll
            for (int j = 0; j < 4; ++j)
                acc[i][j] += a0 * wl0p[j] + a1 * wl1p[j] + h0 * wr0p[j] + h1 * wr1p[j];
        }
    }

    int node0 = blockIdx.x * 64;
#pragma unroll
    for (int i = 0; i < 4; ++i) {
        int n = node0 + n0 + i;
        if (n < N_NODES) {
            ushort4 w;
            w.x = f2b(fmaxf(acc[i][0], 0.f));
            w.y = f2b(fmaxf(acc[i][1], 0.f));
            w.z = f2b(fmaxf(acc[i][2], 0.f));
            w.w = f2b(fmaxf(acc[i][3], 0.f));
            *(ushort4*)(outb + (size_t)n * HID + c0) = w;
        }
    }
}

// ---- head v2: out = h @ Wlin + blin, LDS-tiled, fp32 out ------------------
__global__ void __launch_bounds__(256) head_v2(
        const ushort_t* __restrict__ hb, const float* __restrict__ W,
        const float* __restrict__ bias, float* __restrict__ out) {
    __shared__ float sWo[HID * OUT_CH];
    __shared__ ushort_t sH[64 * SAP];
    __shared__ float sb[OUT_CH];
    int tid = threadIdx.x;
    {
        const float4* W4 = (const float4*)W;
        float4* sW4 = (float4*)sWo;
        for (int i = tid; i < HID * OUT_CH / 4; i += 256) sW4[i] = W4[i];
    }
    if (tid < OUT_CH) sb[tid] = bias[tid];
    size_t tbase = (size_t)blockIdx.x * 64 * HID;
    {   // 512 chunks: 2 per thread (fixed from p<4)
        const int4* gh = (const int4*)(hb + tbase);
#pragma unroll
        for (int p = 0; p < 2; ++p) {
            int q = tid + 256 * p;
            int r = q >> 3, u = q & 7;
            *(int4*)(sH + r * SAP + u * 8) = gh[q];
        }
    }
    __syncthreads();

    int c0 = (tid & 7) << 2;        // 0..28
    int n0 = (tid >> 3) << 1;       // 0..62
    float acc[2][4];
#pragma unroll
    for (int i = 0; i < 2; ++i)
#pragma unroll
        for (int j = 0; j < 4; ++j) acc[i][j] = sb[c0 + j];

#pragma unroll 4
    for (int kk = 0; kk < 32; ++kk) {
        float4 w0 = *(const float4*)&sWo[(2 * kk) * OUT_CH + c0];
        float4 w1 = *(const float4*)&sWo[(2 * kk + 1) * OUT_CH + c0];
        const float* w0p = (const float*)&w0;
        const float* w1p = (const float*)&w1;
#pragma unroll
        for (int i = 0; i < 2; ++i) {
            unsigned uh = *(const unsigned*)(sH + (n0 + i) * SAP + 2 * kk);
            float h0 = blo(uh), h1 = bhi(uh);
#pragma unroll
            for (int j = 0; j < 4; ++j) acc[i][j] += h0 * w0p[j] + h1 * w1p[j];
        }
    }

    int node0 = blockIdx.x * 64;
#pragma unroll
    for (int i = 0; i < 2; ++i) {
        int n = node0 + n0 + i;
        if (n < N_NODES) {
            float4 o4;
            o4.x = acc[i][0]; o4.y = acc[i][1]; o4.z = acc[i][2]; o4.w = acc[i][3];
            *(float4*)(out + (size_t)n * OUT_CH + c0) = o4;
        }
    }
}

extern "C" void kernel_launch(void* const* d_in, const int* in_sizes, int n_in,
                              void* d_out, int out_size, void* d_ws, size_t ws_size,
                              hipStream_t stream) {
    const float* x    = (const float*)d_in[0];
    const int*   ei   = (const int*)d_in[1];
    const float* Wl1  = (const float*)d_in[2];
    const float* Wr1  = (const float*)d_in[3];
    const float* b1   = (const float*)d_in[4];
    const float* Wl2  = (const float*)d_in[5];
    const float* Wr2  = (const float*)d_in[6];
    const float* b2   = (const float*)d_in[7];
    const float* Wl3  = (const float*)d_in[8];
    const float* Wr3  = (const float*)d_in[9];
    const float* b3   = (const float*)d_in[10];
    const float* Wlin = (const float*)d_in[11];
    const float* blin = (const float*)d_in[12];
    float* out = (float*)d_out;

    // workspace layout (4-byte units), ~33 MB; tile overreads land in slack.
    int* ip              = (int*)d_ws;
    int* flag            = ip;                          // 128
    unsigned int* offpk  = (unsigned int*)(flag + 128); // 100096
    int* bbase           = (int*)(offpk + 100096);      // 256
    int* btot            = bbase + 256;                 // 256
    int* histG           = btot + 256;                  // NB*P = 200704
    int* csr             = histG + NB * P;              // 1600000
    ushort_t* aggb       = (ushort_t*)(csr + N_EDGES);  // 6.4M bf16 + 8192 slack
    ushort_t* featb      = aggb + 6408192;              // 6.4M bf16 + 8192 slack
    int* bkt             = (int*)aggb;  // bucket records alias aggb (dead until gather)

    const int CONV_BLOCKS   = (N_NODES * HID / 4) / 256; // 6250
    const int GATHER_BLOCKS = (N_NODES + 3) / 4;         // 25000
    const int TILE_BLOCKS   = (N_NODES + 63) / 64;       // 1563

    // x -> bf16, CSR build (deterministic radix partition + per-bucket fill)
    convert_kernel<<<CONV_BLOCKS, 256, 0, stream>>>(x, featb);
    detect_kernel<<<1, 64, 0, stream>>>(ei, flag);
    hist_kernel<<<P, 256, 0, stream>>>(ei, flag, histG);
    scan_kernel<<<NB, 256, 0, stream>>>(histG, btot);
    base_scan_kernel<<<1, 256, 0, stream>>>(btot, bbase);
    place_kernel<<<P, 256, 0, stream>>>(ei, flag, histG, bbase, bkt);
    bucket_fill_kernel<<<NB, 256, 0, stream>>>(bbase, btot, bkt, csr, offpk);

    // layer 1 (root = bf16 x in featb; in-place featb output is block-local)
    gather_kernel<<<GATHER_BLOCKS, 256, 0, stream>>>(featb, offpk, csr, aggb);
    layer_v2<<<TILE_BLOCKS, 256, 0, stream>>>(aggb, featb, Wl1, Wr1, b1, featb);

    // layer 2
    gather_kernel<<<GATHER_BLOCKS, 256, 0, stream>>>(featb, offpk, csr, aggb);
    layer_v2<<<TILE_BLOCKS, 256, 0, stream>>>(aggb, featb, Wl2, Wr2, b2, featb);

    // layer 3
    gather_kernel<<<GATHER_BLOCKS, 256, 0, stream>>>(featb, offpk, csr, aggb);
    layer_v2<<<TILE_BLOCKS, 256, 0, stream>>>(aggb, featb, Wl3, Wr3, b3, featb);

    // head
    head_v2<<<TILE_BLOCKS, 256, 0, stream>>>(featb, Wlin, blin, out);
}

// Round 11
// 369.897 us; speedup vs baseline: 3.6048x; 1.0234x over previous
//
#include <hip/hip_runtime.h>
#include <hip/hip_bf16.h>

#define N_NODES 100000
#define N_EDGES 1600000
#define HID 64
#define OUT_CH 32

// Deterministic radix partition into dst buckets. Zero global atomics
// (R5: contended global cursors serialize device-wide at ~6 ns/atomic).
#define NB 196           // ceil(100000/512) buckets of 512 consecutive dst nodes
#define P 1024           // partition blocks
#define EPP ((N_EDGES + P - 1) / P)   // 1563 edges per block
#define BKCAP 10240      // LDS csr staging cap (bucket mean 8192, sigma ~90)
#define SAP 66           // bf16 tile pitch (+2 pad: conflict-free row reads)

typedef unsigned short ushort_t;

// bf16 helpers (RNE)
__device__ __forceinline__ ushort_t f2b(float f) {
    union { float f; unsigned u; } un; un.f = f;
    unsigned r = un.u + 0x7FFF + ((un.u >> 16) & 1);
    return (ushort_t)(r >> 16);
}
__device__ __forceinline__ float b2f(ushort_t u) {
    union { unsigned u; float f; } un; un.u = ((unsigned)u) << 16;
    return un.f;
}
__device__ __forceinline__ float blo(unsigned u) {
    union { unsigned u; float f; } un; un.u = u << 16; return un.f;
}
__device__ __forceinline__ float bhi(unsigned u) {
    union { unsigned u; float f; } un; un.u = u & 0xFFFF0000u; return un.f;
}

__device__ __forceinline__ int get_dst(const int* __restrict__ ei, int is64, int e) {
    return is64 ? ((const int2*)ei)[N_EDGES + e].x : ei[N_EDGES + e];
}
__device__ __forceinline__ int get_src(const int* __restrict__ ei, int is64, int e) {
    return is64 ? ((const int2*)ei)[e].x : ei[e];
}

// ---- convert x -> bf16; block CONV_BLOCKS runs the edge-dtype probe -------
#define CONV_BLOCKS ((N_NODES * HID / 4) / 256)   // 6250
__global__ void __launch_bounds__(256) convert_detect_kernel(
        const float* __restrict__ x, ushort_t* __restrict__ xb,
        const int* __restrict__ ei, int* __restrict__ flag) {
    if (blockIdx.x == CONV_BLOCKS) {   // detect: int64 => odd 32-bit words all 0
        int i = threadIdx.x;
        if (i < 64) {
            int v = ei[2 * i + 1];
            unsigned long long ball = __ballot(v == 0);
            if (i == 0) *flag = (ball == ~0ull) ? 1 : 0;
        }
        return;
    }
    int i = blockIdx.x * 256 + threadIdx.x;
    float4 v = ((const float4*)x)[i];
    ushort4 o;
    o.x = f2b(v.x); o.y = f2b(v.y); o.z = f2b(v.z); o.w = f2b(v.w);
    ((ushort4*)xb)[i] = o;
}

// ---- pass 1: per-block bucket histograms ----------------------------------
__global__ void __launch_bounds__(256) hist_kernel(
        const int* __restrict__ ei, const int* __restrict__ flag,
        int* __restrict__ histG) {
    __shared__ int lh[NB];
    int tid = threadIdx.x;
    for (int i = tid; i < NB; i += 256) lh[i] = 0;
    __syncthreads();
    int is64 = *flag;
    int e0 = blockIdx.x * EPP;
    int e1 = min(e0 + EPP, N_EDGES);
    for (int e = e0 + tid; e < e1; e += 256) {
        int d = get_dst(ei, is64, e);
        atomicAdd(&lh[d >> 9], 1);
    }
    __syncthreads();
    for (int i = tid; i < NB; i += 256) histG[i * P + blockIdx.x] = lh[i];
}

// ---- per-bucket exclusive scan over P block-counts (4 elems/thread) -------
__global__ void __launch_bounds__(256) scan_kernel(int* __restrict__ histG,
                                                   int* __restrict__ btot) {
    __shared__ int ps[256];
    int b = blockIdx.x;
    int tid = threadIdx.x;
    int base4 = b * P + 4 * tid;
    int v0 = histG[base4], v1 = histG[base4 + 1], v2 = histG[base4 + 2], v3 = histG[base4 + 3];
    int pv = v0 + v1 + v2 + v3;
    ps[tid] = pv;
    __syncthreads();
    for (int d = 1; d < 256; d <<= 1) {
        int t = (tid >= d) ? ps[tid - d] : 0;
        __syncthreads();
        ps[tid] += t;
        __syncthreads();
    }
    int e = ps[tid] - pv;
    histG[base4] = e; e += v0;
    histG[base4 + 1] = e; e += v1;
    histG[base4 + 2] = e; e += v2;
    histG[base4 + 3] = e;
    if (tid == 255) btot[b] = ps[255];
}

// ---- exclusive scan of 196 bucket totals -> dense bucket bases ------------
__global__ void base_scan_kernel(const int* __restrict__ btot, int* __restrict__ bbase) {
    __shared__ int s[256];
    int tid = threadIdx.x;
    int v = (tid < NB) ? btot[tid] : 0;
    s[tid] = v;
    __syncthreads();
    for (int d = 1; d < 256; d <<= 1) {
        int t = (tid >= d) ? s[tid - d] : 0;
        __syncthreads();
        s[tid] += t;
        __syncthreads();
    }
    if (tid < NB) bbase[tid] = s[tid] - v;
}

// ---- pass 2: place records at deterministic offsets (LDS cursors only) ----
// record = (dst&511)<<17 | src
__global__ void __launch_bounds__(256) place_kernel(
        const int* __restrict__ ei, const int* __restrict__ flag,
        const int* __restrict__ histG, const int* __restrict__ bbase,
        int* __restrict__ bkt) {
    __shared__ int lcur[NB];
    int tid = threadIdx.x;
    for (int i = tid; i < NB; i += 256)
        lcur[i] = bbase[i] + histG[i * P + blockIdx.x];
    __syncthreads();
    int is64 = *flag;
    int e0 = blockIdx.x * EPP;
    int e1 = min(e0 + EPP, N_EDGES);
    for (int e = e0 + tid; e < e1; e += 256) {
        int s = get_src(ei, is64, e);
        int d = get_dst(ei, is64, e);
        int val = ((d & 511) << 17) | s;
        int p = atomicAdd(&lcur[d >> 9], 1);
        bkt[p] = val;
    }
}

// ---- per-bucket csr build in LDS + packed off|deg -------------------------
// offpk[n] = (abs_off & 0x1FFFFF) | (deg << 21)
__global__ void __launch_bounds__(256) bucket_fill_kernel(
        const int* __restrict__ bbase, const int* __restrict__ btot,
        const int* __restrict__ bkt, int* __restrict__ csr,
        unsigned int* __restrict__ offpk) {
    __shared__ int lcnt[512];
    __shared__ int loff[512];
    __shared__ int lcur[512];
    __shared__ int ps[256];
    __shared__ int scsr[BKCAP];
    int b = blockIdx.x;
    int tid = threadIdx.x;
    int base = bbase[b];
    int m = btot[b];
    int n0 = b << 9;
    int nn = min(512, N_NODES - n0);

    lcnt[tid] = 0;
    lcnt[tid + 256] = 0;
    __syncthreads();
    for (int i = tid; i < m; i += 256) atomicAdd(&lcnt[bkt[base + i] >> 17], 1);
    __syncthreads();
    int a0 = lcnt[2 * tid], a1 = lcnt[2 * tid + 1];
    int pv = a0 + a1;
    ps[tid] = pv;
    __syncthreads();
    for (int d = 1; d < 256; d <<= 1) {
        int t = (tid >= d) ? ps[tid - d] : 0;
        __syncthreads();
        ps[tid] += t;
        __syncthreads();
    }
    int excl = ps[tid] - pv;
    loff[2 * tid] = excl;
    loff[2 * tid + 1] = excl + a0;
    lcur[2 * tid] = excl;
    lcur[2 * tid + 1] = excl + a0;
    __syncthreads();
    bool fit = (m <= BKCAP);
    for (int i = tid; i < m; i += 256) {
        int val = bkt[base + i];
        int dl = val >> 17;
        int p = atomicAdd(&lcur[dl], 1);
        if (fit) scsr[p] = val & 0x1FFFF;
        else csr[base + p] = val & 0x1FFFF;
    }
    __syncthreads();
    if (fit)
        for (int i = tid; i < m; i += 256) csr[base + i] = scsr[i];
    for (int i = tid; i < nn; i += 256)
        offpk[n0 + i] = (unsigned int)((base + loff[i]) | (lcnt[i] << 21));
}

// ---- gather v3: 4 edges per wave-iteration --------------------------------
// Quarter-wave (16 lanes) owns one edge; lane loads int2 = 4 bf16 channels
// (2 full 128B rows per unrolled load pair). Cuts per-edge instr ~4x vs the
// 1-edge/iter scheme (R10: VALUBusy 57%). Quarter partials folded with
// 2 shfl_xor steps; lanes 0-15 store ushort4.
__global__ void __launch_bounds__(256) gather_kernel(
        const ushort_t* __restrict__ hb, const unsigned int* __restrict__ offpk,
        const int* __restrict__ csr, ushort_t* __restrict__ aggb) {
    int node = blockIdx.x * 4 + (threadIdx.x >> 6);
    if (node >= N_NODES) return;
    int o = threadIdx.x & 63;
    int q = o >> 4;           // quarter 0..3 (edge slot)
    int l = o & 15;           // channel group: channels 4l..4l+3
    unsigned int v = offpk[node];
    int off0 = (int)(v & 0x1FFFFFu);
    int cnt = (int)(v >> 21);
    float a0 = 0.f, a1 = 0.f, a2 = 0.f, a3 = 0.f;
    int base = off0;
    int rem = cnt;
    while (rem > 0) {
        int take = min(rem, 64);
        int idxv = (o < take) ? csr[base + o] : 0;
        int j = 0;
        for (; j + 8 <= take; j += 8) {
            int i0 = __shfl(idxv, j + q);
            int i1 = __shfl(idxv, j + 4 + q);
            int2 u0 = ((const int2*)(hb + (size_t)i0 * HID))[l];
            int2 u1 = ((const int2*)(hb + (size_t)i1 * HID))[l];
            a0 += blo(u0.x) + blo(u1.x);
            a1 += bhi(u0.x) + bhi(u1.x);
            a2 += blo(u0.y) + blo(u1.y);
            a3 += bhi(u0.y) + bhi(u1.y);
        }
        for (; j < take; j += 4) {
            int e = j + q;
            bool valid = (e < take);
            int idx = __shfl(idxv, valid ? e : 0);
            if (valid) {
                int2 u = ((const int2*)(hb + (size_t)idx * HID))[l];
                a0 += blo(u.x); a1 += bhi(u.x);
                a2 += blo(u.y); a3 += bhi(u.y);
            }
        }
        base += take;
        rem -= take;
    }
    a0 += __shfl_xor(a0, 16); a0 += __shfl_xor(a0, 32);
    a1 += __shfl_xor(a1, 16); a1 += __shfl_xor(a1, 32);
    a2 += __shfl_xor(a2, 16); a2 += __shfl_xor(a2, 32);
    a3 += __shfl_xor(a3, 16); a3 += __shfl_xor(a3, 32);
    if (o < 16) {
        float inv = 1.f / fmaxf((float)cnt, 1.f);
        ushort4 w;
        w.x = f2b(a0 * inv); w.y = f2b(a1 * inv);
        w.z = f2b(a2 * inv); w.w = f2b(a3 * inv);
        *(ushort4*)(aggb + (size_t)node * HID + l * 4) = w;
    }
}

// ---- layer v2: relu(agg@Wl + h@Wr + b) -> bf16, conflict-free LDS ---------
// 64x64 ushort tile = 512 int4 chunks => staging loop p<2 (R9 bug: p<4).
__global__ void __launch_bounds__(256) layer_v2(
        const ushort_t* __restrict__ aggb, const ushort_t* __restrict__ rootb,
        const float* __restrict__ Wl, const float* __restrict__ Wr,
        const float* __restrict__ bias, ushort_t* outb) {
    __shared__ float sWl[HID * HID];
    __shared__ float sWr[HID * HID];
    __shared__ ushort_t sA[64 * SAP];
    __shared__ ushort_t sH[64 * SAP];
    __shared__ float sb[HID];
    int tid = threadIdx.x;
    {
        const float4* Wl4 = (const float4*)Wl;
        const float4* Wr4 = (const float4*)Wr;
        float4* sWl4 = (float4*)sWl;
        float4* sWr4 = (float4*)sWr;
        for (int i = tid; i < HID * HID / 4; i += 256) {
            sWl4[i] = Wl4[i];
            sWr4[i] = Wr4[i];
        }
    }
    if (tid < HID) sb[tid] = bias[tid];
    size_t tbase = (size_t)blockIdx.x * 64 * HID;
    {
        const int4* ga = (const int4*)(aggb + tbase);
        const int4* gh = (const int4*)(rootb + tbase);
#pragma unroll
        for (int p = 0; p < 2; ++p) {
            int q = tid + 256 * p;          // chunk 0..511
            int r = q >> 3, u = q & 7;
            *(int4*)(sA + r * SAP + u * 8) = ga[q];
            *(int4*)(sH + r * SAP + u * 8) = gh[q];
        }
    }
    __syncthreads();

    int c0 = (tid & 15) << 2;
    int n0 = (tid >> 4) << 2;
    float acc[4][4];
#pragma unroll
    for (int i = 0; i < 4; ++i)
#pragma unroll
        for (int j = 0; j < 4; ++j) acc[i][j] = sb[c0 + j];

#pragma unroll 4
    for (int kk = 0; kk < 32; ++kk) {
        float4 wl0 = *(const float4*)&sWl[(2 * kk) * HID + c0];
        float4 wl1 = *(const float4*)&sWl[(2 * kk + 1) * HID + c0];
        float4 wr0 = *(const float4*)&sWr[(2 * kk) * HID + c0];
        float4 wr1 = *(const float4*)&sWr[(2 * kk + 1) * HID + c0];
        const float* wl0p = (const float*)&wl0;
        const float* wl1p = (const float*)&wl1;
        const float* wr0p = (const float*)&wr0;
        const float* wr1p = (const float*)&wr1;
#pragma unroll
        for (int i = 0; i < 4; ++i) {
            unsigned ua = *(const unsigned*)(sA + (n0 + i) * SAP + 2 * kk);
            unsigned uh = *(const unsigned*)(sH + (n0 + i) * SAP + 2 * kk);
            float a0 = blo(ua), a1 = bhi(ua);
            float h0 = blo(uh), h1 = bhi(uh);
#pragma unroll
            for (int j = 0; j < 4; ++j)
                acc[i][j] += a0 * wl0p[j] + a1 * wl1p[j] + h0 * wr0p[j] + h1 * wr1p[j];
        }
    }

    int node0 = blockIdx.x * 64;
#pragma unroll
    for (int i = 0; i < 4; ++i) {
        int n = node0 + n0 + i;
        if (n < N_NODES) {
            ushort4 w;
            w.x = f2b(fmaxf(acc[i][0], 0.f));
            w.y = f2b(fmaxf(acc[i][1], 0.f));
            w.z = f2b(fmaxf(acc[i][2], 0.f));
            w.w = f2b(fmaxf(acc[i][3], 0.f));
            *(ushort4*)(outb + (size_t)n * HID + c0) = w;
        }
    }
}

// ---- head v2: out = h @ Wlin + blin, LDS-tiled, fp32 out ------------------
__global__ void __launch_bounds__(256) head_v2(
        const ushort_t* __restrict__ hb, const float* __restrict__ W,
        const float* __restrict__ bias, float* __restrict__ out) {
    __shared__ float sWo[HID * OUT_CH];
    __shared__ ushort_t sH[64 * SAP];
    __shared__ float sb[OUT_CH];
    int tid = threadIdx.x;
    {
        const float4* W4 = (const float4*)W;
        float4* sW4 = (float4*)sWo;
        for (int i = tid; i < HID * OUT_CH / 4; i += 256) sW4[i] = W4[i];
    }
    if (tid < OUT_CH) sb[tid] = bias[tid];
    size_t tbase = (size_t)blockIdx.x * 64 * HID;
    {
        const int4* gh = (const int4*)(hb + tbase);
#pragma unroll
        for (int p = 0; p < 2; ++p) {
            int q = tid + 256 * p;
            int r = q >> 3, u = q & 7;
            *(int4*)(sH + r * SAP + u * 8) = gh[q];
        }
    }
    __syncthreads();

    int c0 = (tid & 7) << 2;
    int n0 = (tid >> 3) << 1;
    float acc[2][4];
#pragma unroll
    for (int i = 0; i < 2; ++i)
#pragma unroll
        for (int j = 0; j < 4; ++j) acc[i][j] = sb[c0 + j];

#pragma unroll 4
    for (int kk = 0; kk < 32; ++kk) {
        float4 w0 = *(const float4*)&sWo[(2 * kk) * OUT_CH + c0];
        float4 w1 = *(const float4*)&sWo[(2 * kk + 1) * OUT_CH + c0];
        const float* w0p = (const float*)&w0;
        const float* w1p = (const float*)&w1;
#pragma unroll
        for (int i = 0; i < 2; ++i) {
            unsigned uh = *(const unsigned*)(sH + (n0 + i) * SAP + 2 * kk);
            float h0 = blo(uh), h1 = bhi(uh);
#pragma unroll
            for (int j = 0; j < 4; ++j) acc[i][j] += h0 * w0p[j] + h1 * w1p[j];
        }
    }

    int node0 = blockIdx.x * 64;
#pragma unroll
    for (int i = 0; i < 2; ++i) {
        int n = node0 + n0 + i;
        if (n < N_NODES) {
            float4 o4;
            o4.x = acc[i][0]; o4.y = acc[i][1]; o4.z = acc[i][2]; o4.w = acc[i][3];
            *(float4*)(out + (size_t)n * OUT_CH + c0) = o4;
        }
    }
}

extern "C" void kernel_launch(void* const* d_in, const int* in_sizes, int n_in,
                              void* d_out, int out_size, void* d_ws, size_t ws_size,
                              hipStream_t stream) {
    const float* x    = (const float*)d_in[0];
    const int*   ei   = (const int*)d_in[1];
    const float* Wl1  = (const float*)d_in[2];
    const float* Wr1  = (const float*)d_in[3];
    const float* b1   = (const float*)d_in[4];
    const float* Wl2  = (const float*)d_in[5];
    const float* Wr2  = (const float*)d_in[6];
    const float* b2   = (const float*)d_in[7];
    const float* Wl3  = (const float*)d_in[8];
    const float* Wr3  = (const float*)d_in[9];
    const float* b3   = (const float*)d_in[10];
    const float* Wlin = (const float*)d_in[11];
    const float* blin = (const float*)d_in[12];
    float* out = (float*)d_out;

    // workspace layout (4-byte units), ~33 MB; tile overreads land in slack.
    int* ip              = (int*)d_ws;
    int* flag            = ip;                          // 128
    unsigned int* offpk  = (unsigned int*)(flag + 128); // 100096
    int* bbase           = (int*)(offpk + 100096);      // 256
    int* btot            = bbase + 256;                 // 256
    int* histG           = btot + 256;                  // NB*P = 200704
    int* csr             = histG + NB * P;              // 1600000
    ushort_t* aggb       = (ushort_t*)(csr + N_EDGES);  // 6.4M bf16 + 8192 slack
    ushort_t* featb      = aggb + 6408192;              // 6.4M bf16 + 8192 slack
    int* bkt             = (int*)aggb;  // bucket records alias aggb (dead until gather)

    const int GATHER_BLOCKS = (N_NODES + 3) / 4;         // 25000
    const int TILE_BLOCKS   = (N_NODES + 63) / 64;       // 1563

    // x -> bf16 (+edge dtype probe), then deterministic radix CSR build
    convert_detect_kernel<<<CONV_BLOCKS + 1, 256, 0, stream>>>(x, featb, ei, flag);
    hist_kernel<<<P, 256, 0, stream>>>(ei, flag, histG);
    scan_kernel<<<NB, 256, 0, stream>>>(histG, btot);
    base_scan_kernel<<<1, 256, 0, stream>>>(btot, bbase);
    place_kernel<<<P, 256, 0, stream>>>(ei, flag, histG, bbase, bkt);
    bucket_fill_kernel<<<NB, 256, 0, stream>>>(bbase, btot, bkt, csr, offpk);

    // layer 1 (root = bf16 x in featb; in-place featb output is block-local)
    gather_kernel<<<GATHER_BLOCKS, 256, 0, stream>>>(featb, offpk, csr, aggb);
    layer_v2<<<TILE_BLOCKS, 256, 0, stream>>>(aggb, featb, Wl1, Wr1, b1, featb);

    // layer 2
    gather_kernel<<<GATHER_BLOCKS, 256, 0, stream>>>(featb, offpk, csr, aggb);
    layer_v2<<<TILE_BLOCKS, 256, 0, stream>>>(aggb, featb, Wl2, Wr2, b2, featb);

    // layer 3
    gather_kernel<<<GATHER_BLOCKS, 256, 0, stream>>>(featb, offpk, csr, aggb);
    layer_v2<<<TILE_BLOCKS, 256, 0, stream>>>(aggb, featb, Wl3, Wr3, b3, featb);

    // head
    head_v2<<<TILE_BLOCKS, 256, 0, stream>>>(featb, Wlin, blin, out);
}